// Round 11
// baseline (343.422 us; speedup 1.0000x reference)
//
#include <hip/hip_runtime.h>
#include <cmath>

// Shapes (fixed by the problem)
#define AT 225      // Z*Y*X anchors
#define NP 128      // points per sample
#define MT 1024     // B*T
#define NSEL 8
#define HD 64

// workspace float offsets
#define SZ_VOX  (1024u*64u*225u)     // region sized in floats; holds bf16 vox [m][aa][h] (R21)
#define SZ_C1   (1024u*96u*63u)      // region holds bf16 c1 (idx aliases head before conv1)
#define SZ_C2   (1024u*128u*5u)      // unused (c2 lives in LDS now)
#define SZ_VV   (1024u*64u)
#define SZ_XWI  (1024u*256u)         // (w3m aliases its head before k_c23 runs)
#define SZ_W1T  (64u*27u*96u)        // holds w1m (bf16 A-frags, conv1)
#define SZ_W2T  (96u*27u*128u)       // holds w2n (bf16 B-frags, conv2)
#define SZ_W3T  (640u*64u)           // w3t (coalesced conv3 weights)
#define SZ_W2M  (512u)               // pn layer2 B-frags (128 uint4)

#define C2S 98                       // conv2 LDS row stride (us), 49 dw (odd)

typedef __attribute__((ext_vector_type(8))) short bf16x8;
typedef __attribute__((ext_vector_type(4))) float f32x4;

__device__ __forceinline__ float sigm(float x) { return 1.0f / (1.0f + expf(-x)); }

__device__ __forceinline__ unsigned short f2bf(float f) {
    unsigned u = __float_as_uint(f);
    unsigned r = u + 0x7FFF + ((u >> 16) & 1);   // RNE
    return (unsigned short)(r >> 16);
}

// R15: real packed bf16 convert (single v_cvt_pk_bf16_f32; no builtin exists).
// NOTE (R16): v_fma_mix_f32_bf16 does NOT exist on gfx950. Do not retry.
// NOTE (R18): for GLOBAL memory, coalescing beats instruction count.
// NOTE (R20): k_mlpm LDS is hard-capped at 25600 B — 27136 B crossed an
// allocation granule (6 -> 5 blocks/CU) and cost 8%. Never grow it.
__device__ __forceinline__ unsigned pk2(float a, float b) {
    unsigned r;
    asm("v_cvt_pk_bf16_f32 %0, %1, %2" : "=v"(r) : "v"(a), "v"(b));
    return r;
}

// ---------------------------------------------------------------- transpose
__global__ __launch_bounds__(256) void k_transpose(
    const float* __restrict__ w1, const float* __restrict__ w2,
    const float* __restrict__ w3, const float* __restrict__ pnw3,
    const float* __restrict__ pnw2,
    unsigned short* __restrict__ w1m, unsigned short* __restrict__ w2n,
    float* __restrict__ w3t, unsigned short* __restrict__ w3m,
    unsigned short* __restrict__ w2m)
{
    int idx = blockIdx.x * 256 + threadIdx.x;
    if (idx < 20736) {
        int lane = idx & 63, r = idx >> 6;
        int t = r % 6, s = r / 6;
        int o = t * 16 + (lane & 15);
        int kb = s * 32 + (lane >> 4) * 8;
        unsigned int dw[4];
        #pragma unroll
        for (int jd = 0; jd < 4; ++jd) {
            int k0 = kb + 2 * jd, k1 = k0 + 1;
            dw[jd] = (unsigned)f2bf(w1[o * 1728 + (k0 & 63) * 27 + (k0 >> 6)]) |
                     ((unsigned)f2bf(w1[o * 1728 + (k1 & 63) * 27 + (k1 >> 6)]) << 16);
        }
        uint4 v; v.x = dw[0]; v.y = dw[1]; v.z = dw[2]; v.w = dw[3];
        ((uint4*)w1m)[idx] = v;
    } else if (idx < 62208) {
        int q = idx - 20736;
        int lane = q & 63, r = q >> 6;
        int nt = r & 7, s = r >> 3;
        int o = nt * 16 + (lane & 15);
        int kb = s * 32 + (lane >> 4) * 8;
        unsigned int dw[4];
        #pragma unroll
        for (int jd = 0; jd < 4; ++jd) {
            int k0 = kb + 2 * jd, k1 = k0 + 1;
            dw[jd] = (unsigned)f2bf(w2[o * 2592 + (k0 % 96) * 27 + (k0 / 96)]) |
                     ((unsigned)f2bf(w2[o * 2592 + (k1 % 96) * 27 + (k1 / 96)]) << 16);
        }
        uint4 v; v.x = dw[0]; v.y = dw[1]; v.z = dw[2]; v.w = dw[3];
        ((uint4*)w2n)[q] = v;
    } else if (idx < 103168) {
        int k = idx - 62208;
        int u = k & 63, r = k >> 6;
        w3t[k] = w3[u * 640 + r];
    } else if (idx < 103424) {
        int k = idx - 103168;
        int lane = k & 63, nt = k >> 6;
        int n = nt * 16 + (lane & 15);
        int kb = (lane >> 4) * 8;
        unsigned int dw[4];
        #pragma unroll
        for (int jd = 0; jd < 4; ++jd) {
            int k0 = kb + 2 * jd;
            dw[jd] = (unsigned)f2bf(pnw3[k0 * 64 + n]) |
                     ((unsigned)f2bf(pnw3[(k0 + 1) * 64 + n]) << 16);
        }
        uint4 v; v.x = dw[0]; v.y = dw[1]; v.z = dw[2]; v.w = dw[3];
        ((uint4*)w3m)[k] = v;
    } else if (idx < 103552) {
        int k = idx - 103424;
        int lane = k & 63, nt = k >> 6;          // nt 0..1
        int n = nt * 16 + (lane & 15);
        int kb = (lane >> 4) * 8;
        unsigned int dw[4];
        #pragma unroll
        for (int jd = 0; jd < 4; ++jd) {
            int k0 = kb + 2 * jd, k1 = k0 + 1;
            float a = (k0 < 16) ? pnw2[k0 * 32 + n] : 0.0f;
            float b = (k1 < 16) ? pnw2[k1 * 32 + n] : 0.0f;
            dw[jd] = (unsigned)f2bf(a) | ((unsigned)f2bf(b) << 16);
        }
        uint4 v; v.x = dw[0]; v.y = dw[1]; v.z = dw[2]; v.w = dw[3];
        ((uint4*)w2m)[k] = v;
    }
}

// ---------------------------------------------------------------- grouping
// R10-verbatim: selection codegen is bit-stable in THIS compilation context;
// fusing it elsewhere changed FMA contraction and flipped near-tie neighbor
// picks (R11 failure). Do not merge into k_mlpm.
__global__ __launch_bounds__(256) void k_group(
    const float* __restrict__ x, const float* __restrict__ g_loc,
    int* __restrict__ idxbuf)
{
    const int m = blockIdx.x;
    const int tid = threadIdx.x;
    __shared__ float pts[3][NP];

    for (int idx = tid; idx < NP * 5; idx += 256) {
        int n = idx / 5, c = idx % 5;
        if (c < 3) pts[c][n] = x[m * (NP * 5) + idx];
    }
    __syncthreads();

    const float gx = g_loc[m * 2 + 0], gy = g_loc[m * 2 + 1];
    const int grp = tid >> 3, li = tid & 7;

    for (int ca = 0; ca < 256; ca += 32) {
        const int a = ca + grp;
        const bool active = (a < AT);
        const int aa = active ? a : (AT - 1);
        const int azi = aa / 25, ar = aa % 25, ayi = ar / 5, axi = ar % 5;
        const float fx = ((float)axi - 2.0f) * 0.2f + gx;
        const float fy = ((float)ayi - 2.0f) * 0.2f + gy;
        const float fz = (float)azi * 0.22f + 0.1f;
        const float sa = fx * fx + fy * fy + fz * fz;

        float d[16];
        #pragma unroll
        for (int r = 0; r < 16; ++r) {
            int n = li * 16 + r;
            float px = pts[0][n], py = pts[1][n], pz = pts[2][n];
            d[r] = sa - 2.0f * (fx * px + fy * py + fz * pz)
                      + (px * px + py * py + pz * pz);
        }
        int nidx = 0;
        for (int j = 0; j < NSEL; ++j) {
            float best = 1e30f; int bidx = 0;
            #pragma unroll
            for (int r = 0; r < 16; ++r) {
                int n = li * 16 + r;
                if (d[r] < best) { best = d[r]; bidx = n; }
            }
            #pragma unroll
            for (int off = 1; off < 8; off <<= 1) {
                float ov = __shfl_xor(best, off);
                int   oi = __shfl_xor(bidx, off);
                if (ov < best || (ov == best && oi < bidx)) { best = ov; bidx = oi; }
            }
            if (li == j) nidx = bidx;
            if ((bidx >> 4) == li) {
                int slot = bidx & 15;
                #pragma unroll
                for (int r = 0; r < 16; ++r)
                    if (r == slot) d[r] = 1e30f;
            }
        }
        if (active) idxbuf[(m * AT + a) * NSEL + li] = nidx;
    }
}

// ---------------------------------------------------------------- MLP (MFMA L2+L3)
// R21-verbatim (65.5 us measured; LDS 25600 = 6 blocks/CU; anchor-major vox
// stores, one dwordx4 per thread). This kernel is the measurement control —
// no changes this round.
__global__ __launch_bounds__(128) void k_mlpm(
    const float* __restrict__ x, const float* __restrict__ g_loc,
    const int* __restrict__ idxbuf,
    const float* __restrict__ w1, const float* __restrict__ b1,
    const unsigned short* __restrict__ w2m, const float* __restrict__ b2,
    const unsigned short* __restrict__ w3m, const float* __restrict__ b3,
    const float* __restrict__ aw, const float* __restrict__ ab,
    unsigned short* __restrict__ vox, float* __restrict__ attn_out)
{
    const int tid = threadIdx.x;
    const int row0 = blockIdx.x * 128;
    const int row = row0 + tid;

    __shared__ __align__(16) char smem[25600];
    unsigned int*   fbuf = (unsigned int*)smem;              // 8704 B, stride 17 dw
    unsigned int*   f3w  = (unsigned int*)(smem + 8704);     // 16896 B, stride 33 dw
    float*          pts  = (float*)(smem + 8704);            // aliases f3w head
    float*          sbuf = (float*)smem;                     // aliases fbuf head

    const int m0 = row0 / 1800;
    const int m1 = (row0 + 127) / 1800;
    #pragma unroll
    for (int i = tid; i < 640; i += 128) {
        pts[i]       = x[m0 * 640 + i];
        pts[640 + i] = x[m1 * 640 + i];
    }
    __syncthreads();

    // ---- phase A: layer 1 per-thread, pack f1 to fbuf (K 16..31 zeroed) ----
    const int m = row / 1800;
    const int rr = row % 1800;
    const int a = rr >> 3;
    const int base = (m == m0) ? 0 : 640;

    const int azi = a / 25, ar = a % 25, ayi = ar / 5, axi = ar % 5;
    const float gx = g_loc[m * 2 + 0], gy = g_loc[m * 2 + 1];
    const float fx = ((float)axi - 2.0f) * 0.2f + gx;
    const float fy = ((float)ayi - 2.0f) * 0.2f + gy;
    const float fz = (float)azi * 0.22f + 0.1f;

    const int nidx = idxbuf[row];
    const float in0 = pts[base + nidx * 5 + 0] - fx;
    const float in1 = pts[base + nidx * 5 + 1] - fy;
    const float in2 = pts[base + nidx * 5 + 2] - fz;
    const float in3 = pts[base + nidx * 5 + 3];
    const float in4 = pts[base + nidx * 5 + 4];

    float f1v[16];
    #pragma unroll
    for (int j = 0; j < 16; ++j) {
        float s = b1[j];
        s += in0 * w1[0 * 16 + j] + in1 * w1[1 * 16 + j] + in2 * w1[2 * 16 + j]
           + in3 * w1[3 * 16 + j] + in4 * w1[4 * 16 + j];
        f1v[j] = fmaxf(s, 0.0f);
    }
    __syncthreads();   // pts (float) reads complete before f3w (uint) reuse
    #pragma unroll
    for (int kd = 0; kd < 8; ++kd)
        fbuf[tid * 17 + kd] = pk2(f1v[2 * kd], f1v[2 * kd + 1]);
    #pragma unroll
    for (int kd = 8; kd < 16; ++kd)
        fbuf[tid * 17 + kd] = 0u;
    // no barrier: L2 A-frags read only this wave's rows (in-order LDS)

    // ---- phase B: MFMA layers (swapped operands) ----
    const int wv = tid >> 6, lane = tid & 63;
    const int quad = lane >> 4, mcol = lane & 15;

    // layer 2: f2[row][n] for n = nt*16 + quad*4 + reg, row = rowbase + mcol
    bf16x8 w2f[2];
    #pragma unroll
    for (int nt = 0; nt < 2; ++nt) {
        uint4 u = ((const uint4*)w2m)[nt * 64 + lane];
        w2f[nt] = __builtin_bit_cast(bf16x8, u);
    }
    const float4* b24 = (const float4*)b2;
    float4 b2q[2];
    #pragma unroll
    for (int nt = 0; nt < 2; ++nt) b2q[nt] = b24[nt * 4 + quad];

    #pragma unroll
    for (int mt = 0; mt < 4; ++mt) {
        const int rowbase = (wv * 4 + mt) * 16;
        const int abase = (rowbase + mcol) * 17 + quad * 4;
        uint4 au;
        au.x = fbuf[abase + 0]; au.y = fbuf[abase + 1];
        au.z = fbuf[abase + 2]; au.w = fbuf[abase + 3];
        bf16x8 af = __builtin_bit_cast(bf16x8, au);
        #pragma unroll
        for (int nt = 0; nt < 2; ++nt) {
            f32x4 z = (f32x4){0.f, 0.f, 0.f, 0.f};
            f32x4 acc = __builtin_amdgcn_mfma_f32_16x16x32_bf16(w2f[nt], af, z, 0, 0, 0);
            float v0 = fmaxf(acc[0] + b2q[nt].x, 0.0f);
            float v1 = fmaxf(acc[1] + b2q[nt].y, 0.0f);
            float v2 = fmaxf(acc[2] + b2q[nt].z, 0.0f);
            float v3 = fmaxf(acc[3] + b2q[nt].w, 0.0f);
            const int dbase = (rowbase + mcol) * 17 + nt * 8 + quad * 2;
            fbuf[dbase + 0] = pk2(v0, v1);
            fbuf[dbase + 1] = pk2(v2, v3);
        }
    }
    // no barrier: L3 A-frags read only this wave's rows (in-order LDS)

    // layer 3: f3[row][n] for n = nt*16 + quad*4 + reg
    bf16x8 w3f[4];
    #pragma unroll
    for (int nt = 0; nt < 4; ++nt) {
        uint4 u = ((const uint4*)w3m)[nt * 64 + lane];
        w3f[nt] = __builtin_bit_cast(bf16x8, u);
    }
    const float4* b34 = (const float4*)b3;
    float4 b3q[4];
    #pragma unroll
    for (int nt = 0; nt < 4; ++nt) b3q[nt] = b34[nt * 4 + quad];

    #pragma unroll
    for (int mt = 0; mt < 4; ++mt) {
        const int rowbase = (wv * 4 + mt) * 16;
        const int abase = (rowbase + mcol) * 17 + quad * 4;
        uint4 au;
        au.x = fbuf[abase + 0]; au.y = fbuf[abase + 1];
        au.z = fbuf[abase + 2]; au.w = fbuf[abase + 3];
        bf16x8 af = __builtin_bit_cast(bf16x8, au);
        #pragma unroll
        for (int nt = 0; nt < 4; ++nt) {
            f32x4 z = (f32x4){0.f, 0.f, 0.f, 0.f};
            f32x4 acc = __builtin_amdgcn_mfma_f32_16x16x32_bf16(w3f[nt], af, z, 0, 0, 0);
            float v0 = fmaxf(acc[0] + b3q[nt].x, 0.0f);
            float v1 = fmaxf(acc[1] + b3q[nt].y, 0.0f);
            float v2 = fmaxf(acc[2] + b3q[nt].z, 0.0f);
            float v3 = fmaxf(acc[3] + b3q[nt].w, 0.0f);
            const int dbase = (rowbase + mcol) * 33 + nt * 8 + quad * 2;
            f3w[dbase + 0] = pk2(v0, v1);
            f3w[dbase + 1] = pk2(v2, v3);
        }
    }
    // no barrier: phase C reads only this wave's rows (in-order LDS)

    // ---- phase C: score, softmax, weighted sum ----
    const unsigned int* f3dw = (const unsigned int*)f3w;    // row stride 33 dw
    float s0 = 0.f, s1 = 0.f;
    #pragma unroll
    for (int kd = 0; kd < 32; ++kd) {
        unsigned dw = f3dw[tid * 33 + kd];
        s0 = fmaf(__uint_as_float(dw << 16), aw[2 * kd], s0);
        s1 = fmaf(__uint_as_float(dw & 0xFFFF0000u), aw[2 * kd + 1], s1);
    }
    float sc = s0 + s1 + ab[0];

    float mx = sc;
    #pragma unroll
    for (int off = 1; off < 8; off <<= 1) mx = fmaxf(mx, __shfl_xor(mx, off));
    float e = expf(sc - mx);
    float den = e;
    #pragma unroll
    for (int off = 1; off < 8; off <<= 1) den += __shfl_xor(den, off);
    const float at = e / den;
    attn_out[row] = at;

    // lane li owns h = q*16 + li*2 + {0,1}  (conflict-free b32 reads)
    const int lgrp = tid >> 3;
    const int li = tid & 7;
    const int wl = tid & 63;
    float oo[8];
    #pragma unroll
    for (int i = 0; i < 8; ++i) oo[i] = 0.0f;
    #pragma unroll
    for (int ns = 0; ns < 8; ++ns) {
        float atn = __shfl(at, (wl >> 3) * 8 + ns);
        const int rbase = (lgrp * 8 + ns) * 33;
        #pragma unroll
        for (int q = 0; q < 4; ++q) {
            unsigned dw = f3dw[rbase + q * 8 + li];
            oo[2 * q + 0] = fmaf(atn, __uint_as_float(dw << 16), oo[2 * q + 0]);
            oo[2 * q + 1] = fmaf(atn, __uint_as_float(dw & 0xFFFF0000u), oo[2 * q + 1]);
        }
    }
    __syncthreads();   // fence: cross-wave fbuf loads done -> sbuf (alias) writes
    #pragma unroll
    for (int q = 0; q < 4; ++q) {
        sbuf[lgrp * 65 + q * 16 + li * 2 + 0] = oo[2 * q + 0];
        sbuf[lgrp * 65 + q * 16 + li * 2 + 1] = oo[2 * q + 1];
    }
    __syncthreads();   // fence: cross-wave sbuf reads below

    const int al = tid & 15, j = tid >> 4;
    const int ga = (row0 >> 3) + al;
    const int ma = ga / 225, aa2 = ga % 225;
    const int hb = j * 8;
    {
        unsigned p0 = pk2(sbuf[al * 65 + hb + 0], sbuf[al * 65 + hb + 1]);
        unsigned p1 = pk2(sbuf[al * 65 + hb + 2], sbuf[al * 65 + hb + 3]);
        unsigned p2 = pk2(sbuf[al * 65 + hb + 4], sbuf[al * 65 + hb + 5]);
        unsigned p3 = pk2(sbuf[al * 65 + hb + 6], sbuf[al * 65 + hb + 7]);
        uint4 st; st.x = p0; st.y = p1; st.z = p2; st.w = p3;
        // vox[m][aa][h]: 16B-aligned ((ma*225+aa2)*64 + hb is mult of 8 us)
        *(uint4*)(vox + ((size_t)(ma * 225 + aa2) * 64 + hb)) = st;
    }
}

// ---------------------------------------------------------------- conv1 MFMA
// R22: ONE image per block (grid 1024). LDS halves to 29.7 KB and grid
// doubles -> 16 waves/CU (was 8) to hide the K-loop's L2 A-load latency.
// Per-output instruction stream and order unchanged -> bit-identical.
// (Cost: w1m L2 traffic doubles; 331 KB is L2-resident.)
__global__ __launch_bounds__(256) void k_conv1m(
    const unsigned short* __restrict__ vox, const unsigned short* __restrict__ w1m,
    const float* __restrict__ b1, unsigned short* __restrict__ out)
{
    const int m0 = blockIdx.x;
    const int tid = threadIdx.x;
    __shared__ unsigned short voxT[225 * 66];

    {
        const unsigned int* vsrc =
            (const unsigned int*)(vox + (size_t)m0 * 14400);
        for (int i = tid; i < 7200; i += 256) {
            unsigned v = vsrc[i];
            int a0 = i >> 5;              // 32 dws (64 ch) per anchor
            int c2 = (i & 31) * 2;        // even channel
            *(unsigned*)(&voxT[a0 * 66 + c2]) = v;   // 4B-aligned
        }
    }
    __syncthreads();

    const int wv = tid >> 6, lane = tid & 63;
    const int quad = lane >> 4, n = lane & 15;
    const int p = wv * 16 + n;
    const int pe = (p > 62) ? 62 : p;
    const int zo = pe / 9, pr = pe % 9, yo = pr / 3, xo = pr % 3;
    const int basep = zo * 25 + yo * 5 + xo;

    f32x4 acc[6];
    #pragma unroll
    for (int t = 0; t < 6; ++t) acc[t] = (f32x4){0.f, 0.f, 0.f, 0.f};

    const uint4* Aptr = (const uint4*)w1m;

    auto loadB = [&](int s) -> uint4 {
        int tap = s >> 1;
        int dz = tap / 9, tr = tap % 9, dy = tr / 3, dx = tr % 3;
        int rw = basep + dz * 25 + dy * 5 + dx;
        int bidx = rw * 66 + (s & 1) * 32 + quad * 8;
        const unsigned int* vp = (const unsigned int*)(&voxT[0] + bidx);
        uint4 r; r.x = vp[0]; r.y = vp[1]; r.z = vp[2]; r.w = vp[3];
        return r;
    };

    uint4 Acur[6], Anxt[6];
    uint4 Bcur, Bnxt;
    #pragma unroll
    for (int t = 0; t < 6; ++t) Acur[t] = Aptr[t * 64 + lane];
    Bcur = loadB(0);

    for (int s = 0; s < 54; ++s) {
        if ((s & 3) == 0) __syncthreads();   // align waves for L1 A-reuse
        if (s < 53) {
            Bnxt = loadB(s + 1);
            #pragma unroll
            for (int t = 0; t < 6; ++t)
                Anxt[t] = Aptr[((s + 1) * 6 + t) * 64 + lane];
        }
        bf16x8 bf0 = __builtin_bit_cast(bf16x8, Bcur);
        #pragma unroll
        for (int t = 0; t < 6; ++t) {
            bf16x8 af = __builtin_bit_cast(bf16x8, Acur[t]);
            acc[t] = __builtin_amdgcn_mfma_f32_16x16x32_bf16(af, bf0, acc[t], 0, 0, 0);
        }
        #pragma unroll
        for (int t = 0; t < 6; ++t) Acur[t] = Anxt[t];
        Bcur = Bnxt;
    }

    if (p < 63) {
        #pragma unroll
        for (int t = 0; t < 6; ++t) {
            #pragma unroll
            for (int r = 0; r < 4; r += 2) {
                int o = t * 16 + quad * 4 + r;
                unsigned pk = pk2(fmaxf(acc[t][r] + b1[o], 0.0f),
                                  fmaxf(acc[t][r + 1] + b1[o + 1], 0.0f));
                out[m0 * (96 * 63) + o * 63 + p]       = (unsigned short)pk;
                out[m0 * (96 * 63) + (o + 1) * 63 + p] = (unsigned short)(pk >> 16);
            }
        }
    }
}

// ---------------------------------------------------------------- conv2 + conv3 + xwi
// conv2 MFMA as R10 (2 images/block — M-rows pack 2x5 z-outputs; 1 image
// would waste half the MFMA rows). R22: register double-buffer the global
// w2n B-loads (prefetch s+1's pair during s's MFMAs — conv1m's pattern;
// B index needs only s+1, no div). Same loads, same MFMA order ->
// bit-identical. conv3 + xwi: R10 exact summation order; w3t coalesced.
__global__ __launch_bounds__(256) void k_c23(
    const unsigned short* __restrict__ c1, const unsigned short* __restrict__ w2n,
    const float* __restrict__ b2, const float* __restrict__ w3t,
    const float* __restrict__ b3, const float* __restrict__ wi,
    const float* __restrict__ lb, float* __restrict__ xwi)
{
    const int tid = threadIdx.x;
    const int m0 = blockIdx.x * 2;
    __shared__ unsigned short c1T[2 * 63 * C2S];   // 24696 B
    __shared__ float c2l[2][640];                  // 5120 B
    __shared__ float part[2][4][64];               // 2048 B
    __shared__ float vvl[2][64];                   // 512 B

    const unsigned int* csrc = (const unsigned int*)(c1 + (size_t)m0 * 6048);
    for (int i = tid; i < 6048; i += 256) {
        unsigned v = csrc[i];
        int e0 = 2 * i;
        int mi = (i >= 3024);
        int r0 = e0 - mi * 6048, r1 = r0 + 1;
        int o0 = r0 / 63, p0 = r0 - o0 * 63;
        int o1 = r1 / 63, p1 = r1 - o1 * 63;
        c1T[(mi * 63 + p0) * C2S + o0] = (unsigned short)(v & 0xFFFFu);
        c1T[(mi * 63 + p1) * C2S + o1] = (unsigned short)(v >> 16);
    }
    __syncthreads();

    const int wv = tid >> 6, lane = tid & 63;
    const int quad = lane >> 4, ncol = lane & 15;
    const int arow = lane & 15;
    const int mi = (arow < 10) ? arow / 5 : 1;
    const int zo = (arow < 10) ? arow % 5 : 4;

    f32x4 acc[2];
    acc[0] = (f32x4){0.f, 0.f, 0.f, 0.f};
    acc[1] = (f32x4){0.f, 0.f, 0.f, 0.f};
    const uint4* Bptr = (const uint4*)w2n;

    uint4 Bc[2], Bn[2];
    Bc[0] = Bptr[(wv * 2 + 0) * 64 + lane];
    Bc[1] = Bptr[(wv * 2 + 1) * 64 + lane];

    for (int tap = 0; tap < 27; ++tap) {
        const int dz = tap / 9, r9 = tap % 9;
        const int rowb = (mi * 63 + (zo + dz) * 9 + r9) * C2S;
        #pragma unroll
        for (int sub = 0; sub < 3; ++sub) {
            const int s = tap * 3 + sub;
            const unsigned int* ap =
                (const unsigned int*)(c1T + rowb + sub * 32 + quad * 8);
            uint4 au; au.x = ap[0]; au.y = ap[1]; au.z = ap[2]; au.w = ap[3];
            bf16x8 af = __builtin_bit_cast(bf16x8, au);
            if (s < 80) {
                Bn[0] = Bptr[((s + 1) * 8 + wv * 2 + 0) * 64 + lane];
                Bn[1] = Bptr[((s + 1) * 8 + wv * 2 + 1) * 64 + lane];
            }
            #pragma unroll
            for (int nt = 0; nt < 2; ++nt) {
                bf16x8 bf = __builtin_bit_cast(bf16x8, Bc[nt]);
                acc[nt] = __builtin_amdgcn_mfma_f32_16x16x32_bf16(af, bf, acc[nt], 0, 0, 0);
            }
            Bc[0] = Bn[0]; Bc[1] = Bn[1];
        }
    }

    #pragma unroll
    for (int nt = 0; nt < 2; ++nt) {
        const int o = (wv * 2 + nt) * 16 + ncol;
        const float bias = b2[o];
        #pragma unroll
        for (int reg = 0; reg < 4; ++reg) {
            int rr = quad * 4 + reg;
            if (rr < 10)
                c2l[rr / 5][o * 5 + (rr % 5)] = fmaxf(acc[nt][reg] + bias, 0.0f);
        }
    }
    __syncthreads();

    // conv3: R10 order — per image, 4 partials of 160 K each (u=tid&63,
    // kq=tid>>6), sequential fmaf chain, unroll 8.
    {
        const int u = tid & 63, kq = tid >> 6;
        const int k0 = kq * 160;
        #pragma unroll
        for (int mi2 = 0; mi2 < 2; ++mi2) {
            float acc3 = 0.0f;
            #pragma unroll 8
            for (int k = k0; k < k0 + 160; ++k)
                acc3 = fmaf(c2l[mi2][k], w3t[k * 64 + u], acc3);
            part[mi2][kq][u] = acc3;
        }
    }
    __syncthreads();
    if (tid < 128) {
        int mi2 = tid >> 6, u = tid & 63;
        vvl[mi2][u] = b3[u] + ((part[mi2][0][u] + part[mi2][1][u])
                    + (part[mi2][2][u] + part[mi2][3][u]));
    }
    __syncthreads();

    // xwi: R10 order — sequential k 0..63
    #pragma unroll
    for (int mi2 = 0; mi2 < 2; ++mi2) {
        float a2 = lb[tid];
        #pragma unroll
        for (int k = 0; k < 64; ++k)
            a2 = fmaf(vvl[mi2][k], wi[k * 256 + tid], a2);
        xwi[(m0 + mi2) * 256 + tid] = a2;
    }
}

// ---------------------------------------------------------------- LSTM
// R12: software-pipeline the xwi load one step ahead so its global-load
// latency hides under the 64-FMA recurrent dot (values identical).
__global__ __launch_bounds__(256) void k_lstm(
    const float* __restrict__ xwi, const float* __restrict__ whg,
    const float* __restrict__ h0, const float* __restrict__ c0,
    float* __restrict__ avec, float* __restrict__ hn, float* __restrict__ cn)
{
    const int b = blockIdx.x;
    const int j = threadIdx.x;
    __shared__ __align__(16) float hbuf[64];
    __shared__ float gbuf[256];

    float wh[64];
    #pragma unroll
    for (int k = 0; k < 64; ++k) wh[k] = whg[k * 256 + j];

    if (j < 64) hbuf[j] = h0[b * 64 + j];
    float c = (j < 64) ? c0[b * 64 + j] : 0.0f;
    const bool is_tanh_gate = ((j >> 6) == 2);
    __syncthreads();

    const float4* hb4 = (const float4*)hbuf;
    float xt = xwi[(b * 64 + 0) * 256 + j];
    for (int t = 0; t < 64; ++t) {
        float xt_next = (t < 63) ? xwi[(b * 64 + t + 1) * 256 + j] : 0.0f;
        float g = xt;
        float p[4] = {0.f, 0.f, 0.f, 0.f};
        #pragma unroll
        for (int k4 = 0; k4 < 16; ++k4) {
            float4 h4 = hb4[k4];
            int q = k4 & 3;
            p[q] = fmaf(h4.x, wh[4 * k4 + 0], p[q]);
            p[q] = fmaf(h4.y, wh[4 * k4 + 1], p[q]);
            p[q] = fmaf(h4.z, wh[4 * k4 + 2], p[q]);
            p[q] = fmaf(h4.w, wh[4 * k4 + 3], p[q]);
        }
        g += (p[0] + p[1]) + (p[2] + p[3]);
        gbuf[j] = is_tanh_gate ? tanhf(g) : sigm(g);
        __syncthreads();
        if (j < 64) {
            c = gbuf[64 + j] * c + gbuf[j] * gbuf[128 + j];
            float h = gbuf[192 + j] * tanhf(c);
            hbuf[j] = h;
            avec[(b * 64 + t) * 64 + j] = h;
        }
        __syncthreads();
        xt = xt_next;
    }
    if (j < 64) {
        hn[b * 64 + j] = hbuf[j];
        cn[b * 64 + j] = c;
    }
}

// ---------------------------------------------------------------- launch
extern "C" void kernel_launch(void* const* d_in, const int* in_sizes, int n_in,
                              void* d_out, int out_size, void* d_ws, size_t ws_size,
                              hipStream_t stream) {
    const float* x     = (const float*)d_in[0];
    const float* g_loc = (const float*)d_in[1];
    const float* h0    = (const float*)d_in[2];
    const float* c0    = (const float*)d_in[3];
    const float* pn_w1 = (const float*)d_in[4];
    const float* pn_b1 = (const float*)d_in[5];
    const float* pn_w2 = (const float*)d_in[6];
    const float* pn_b2 = (const float*)d_in[7];
    const float* pn_w3 = (const float*)d_in[8];
    const float* pn_b3 = (const float*)d_in[9];
    const float* aw    = (const float*)d_in[10];
    const float* ab    = (const float*)d_in[11];
    const float* vx_w1 = (const float*)d_in[12];
    const float* vx_b1 = (const float*)d_in[13];
    const float* vx_w2 = (const float*)d_in[14];
    const float* vx_b2 = (const float*)d_in[15];
    const float* vx_w3 = (const float*)d_in[16];
    const float* vx_b3 = (const float*)d_in[17];
    const float* lwi   = (const float*)d_in[18];
    const float* lwh   = (const float*)d_in[19];
    const float* lb    = (const float*)d_in[20];

    float* ws  = (float*)d_ws;
    float* voxr = ws;
    float* c1r  = voxr + SZ_VOX;
    float* c2  = c1r + SZ_C1;         // unused (c2 in LDS; layout stability)
    float* vv  = c2 + SZ_C2;          // unused
    float* xwi = vv + SZ_VV;
    float* w1r = xwi + SZ_XWI;
    float* w2r = w1r + SZ_W1T;
    float* w3t = w2r + SZ_W2T;
    float* w2mr = w3t + SZ_W3T;
    unsigned short* voxh = (unsigned short*)voxr;
    unsigned short* c1h  = (unsigned short*)c1r;
    unsigned short* w1m = (unsigned short*)w1r;
    unsigned short* w2n = (unsigned short*)w2r;
    unsigned short* w2m = (unsigned short*)w2mr;
    unsigned short* w3m = (unsigned short*)xwi;  // aliases xwi head; xwi written later
    int*   idxb = (int*)c1r;          // idx lives in the (not-yet-written) c1 region

    float* out   = (float*)d_out;
    float* avec  = out;                   // 65536
    float* attnw = out + 65536;           // 1843200
    float* hn    = out + 65536 + 1843200; // 1024
    float* cn    = hn + 1024;             // 1024

    k_transpose<<<405, 256, 0, stream>>>(vx_w1, vx_w2, vx_w3, pn_w3, pn_w2,
                                         w1m, w2n, w3t, w3m, w2m);
    k_group<<<1024, 256, 0, stream>>>(x, g_loc, idxb);
    k_mlpm<<<14400, 128, 0, stream>>>(x, g_loc, idxb, pn_w1, pn_b1, w2m, pn_b2,
                                      w3m, pn_b3, aw, ab, voxh, attnw);
    k_conv1m<<<1024, 256, 0, stream>>>(voxh, w1m, vx_b1, c1h);
    k_c23<<<512, 256, 0, stream>>>(c1h, w2n, vx_b2, w3t, vx_b3, lwi, lb, xwi);
    k_lstm<<<16, 256, 0, stream>>>(xwi, lwh, h0, c0, avec, hn, cn);
}

// Round 12
// 326.456 us; speedup vs baseline: 1.0520x; 1.0520x over previous
//
#include <hip/hip_runtime.h>
#include <cmath>

// Shapes (fixed by the problem)
#define AT 225      // Z*Y*X anchors
#define NP 128      // points per sample
#define MT 1024     // B*T
#define NSEL 8
#define HD 64

// workspace float offsets
#define SZ_VOX  (1024u*64u*225u)     // region sized in floats; holds bf16 vox [m][aa][h] (R21)
#define SZ_C1   (1024u*96u*63u)      // region holds bf16 c1 (idx aliases head before conv1)
#define SZ_C2   (1024u*128u*5u)      // unused (c2 lives in LDS now)
#define SZ_VV   (1024u*64u)
#define SZ_XWI  (1024u*256u)         // (w3m aliases its head before k_c23 runs)
#define SZ_W1T  (64u*27u*96u)        // holds w1m (bf16 A-frags, conv1)
#define SZ_W2T  (96u*27u*128u)       // holds w2n (bf16 B-frags, conv2)
#define SZ_W3T  (640u*64u)           // w3t (coalesced conv3 weights)
#define SZ_W2M  (512u)               // pn layer2 B-frags (128 uint4)

#define C2S 98                       // conv2 LDS row stride (us), 49 dw (odd)

typedef __attribute__((ext_vector_type(8))) short bf16x8;
typedef __attribute__((ext_vector_type(4))) float f32x4;

__device__ __forceinline__ float sigm(float x) { return 1.0f / (1.0f + expf(-x)); }

__device__ __forceinline__ unsigned short f2bf(float f) {
    unsigned u = __float_as_uint(f);
    unsigned r = u + 0x7FFF + ((u >> 16) & 1);   // RNE
    return (unsigned short)(r >> 16);
}

// R15: real packed bf16 convert (single v_cvt_pk_bf16_f32; no builtin exists).
// NOTE (R16): v_fma_mix_f32_bf16 does NOT exist on gfx950. Do not retry.
// NOTE (R18): for GLOBAL memory, coalescing beats instruction count.
// NOTE (R20): k_mlpm LDS is hard-capped at 25600 B (granule: 6 blocks/CU).
// NOTE (R22): k_conv1m is A-load L1-BW bound — waves share w1m via L1, so
// FEWER blocks (2 images/block) halves per-CU A-traffic. Do not split.
__device__ __forceinline__ unsigned pk2(float a, float b) {
    unsigned r;
    asm("v_cvt_pk_bf16_f32 %0, %1, %2" : "=v"(r) : "v"(a), "v"(b));
    return r;
}

// ---------------------------------------------------------------- transpose
__global__ __launch_bounds__(256) void k_transpose(
    const float* __restrict__ w1, const float* __restrict__ w2,
    const float* __restrict__ w3, const float* __restrict__ pnw3,
    const float* __restrict__ pnw2,
    unsigned short* __restrict__ w1m, unsigned short* __restrict__ w2n,
    float* __restrict__ w3t, unsigned short* __restrict__ w3m,
    unsigned short* __restrict__ w2m)
{
    int idx = blockIdx.x * 256 + threadIdx.x;
    if (idx < 20736) {
        int lane = idx & 63, r = idx >> 6;
        int t = r % 6, s = r / 6;
        int o = t * 16 + (lane & 15);
        int kb = s * 32 + (lane >> 4) * 8;
        unsigned int dw[4];
        #pragma unroll
        for (int jd = 0; jd < 4; ++jd) {
            int k0 = kb + 2 * jd, k1 = k0 + 1;
            dw[jd] = (unsigned)f2bf(w1[o * 1728 + (k0 & 63) * 27 + (k0 >> 6)]) |
                     ((unsigned)f2bf(w1[o * 1728 + (k1 & 63) * 27 + (k1 >> 6)]) << 16);
        }
        uint4 v; v.x = dw[0]; v.y = dw[1]; v.z = dw[2]; v.w = dw[3];
        ((uint4*)w1m)[idx] = v;
    } else if (idx < 62208) {
        int q = idx - 20736;
        int lane = q & 63, r = q >> 6;
        int nt = r & 7, s = r >> 3;
        int o = nt * 16 + (lane & 15);
        int kb = s * 32 + (lane >> 4) * 8;
        unsigned int dw[4];
        #pragma unroll
        for (int jd = 0; jd < 4; ++jd) {
            int k0 = kb + 2 * jd, k1 = k0 + 1;
            dw[jd] = (unsigned)f2bf(w2[o * 2592 + (k0 % 96) * 27 + (k0 / 96)]) |
                     ((unsigned)f2bf(w2[o * 2592 + (k1 % 96) * 27 + (k1 / 96)]) << 16);
        }
        uint4 v; v.x = dw[0]; v.y = dw[1]; v.z = dw[2]; v.w = dw[3];
        ((uint4*)w2n)[q] = v;
    } else if (idx < 103168) {
        int k = idx - 62208;
        int u = k & 63, r = k >> 6;
        w3t[k] = w3[u * 640 + r];
    } else if (idx < 103424) {
        int k = idx - 103168;
        int lane = k & 63, nt = k >> 6;
        int n = nt * 16 + (lane & 15);
        int kb = (lane >> 4) * 8;
        unsigned int dw[4];
        #pragma unroll
        for (int jd = 0; jd < 4; ++jd) {
            int k0 = kb + 2 * jd;
            dw[jd] = (unsigned)f2bf(pnw3[k0 * 64 + n]) |
                     ((unsigned)f2bf(pnw3[(k0 + 1) * 64 + n]) << 16);
        }
        uint4 v; v.x = dw[0]; v.y = dw[1]; v.z = dw[2]; v.w = dw[3];
        ((uint4*)w3m)[k] = v;
    } else if (idx < 103552) {
        int k = idx - 103424;
        int lane = k & 63, nt = k >> 6;          // nt 0..1
        int n = nt * 16 + (lane & 15);
        int kb = (lane >> 4) * 8;
        unsigned int dw[4];
        #pragma unroll
        for (int jd = 0; jd < 4; ++jd) {
            int k0 = kb + 2 * jd, k1 = k0 + 1;
            float a = (k0 < 16) ? pnw2[k0 * 32 + n] : 0.0f;
            float b = (k1 < 16) ? pnw2[k1 * 32 + n] : 0.0f;
            dw[jd] = (unsigned)f2bf(a) | ((unsigned)f2bf(b) << 16);
        }
        uint4 v; v.x = dw[0]; v.y = dw[1]; v.z = dw[2]; v.w = dw[3];
        ((uint4*)w2m)[k] = v;
    }
}

// ---------------------------------------------------------------- grouping
// R10-verbatim: selection codegen is bit-stable in THIS compilation context;
// fusing it elsewhere changed FMA contraction and flipped near-tie neighbor
// picks (R11 failure). Do not merge into k_mlpm.
// R22 measurement: ~65 us, VALUBusy ~69%, HBM 1.7% — issue-bound; the
// exec-mask makes winner-only-rescan optimizations wave-cost-neutral, so
// the selection loop is near its SIMD floor. Leave as is.
__global__ __launch_bounds__(256) void k_group(
    const float* __restrict__ x, const float* __restrict__ g_loc,
    int* __restrict__ idxbuf)
{
    const int m = blockIdx.x;
    const int tid = threadIdx.x;
    __shared__ float pts[3][NP];

    for (int idx = tid; idx < NP * 5; idx += 256) {
        int n = idx / 5, c = idx % 5;
        if (c < 3) pts[c][n] = x[m * (NP * 5) + idx];
    }
    __syncthreads();

    const float gx = g_loc[m * 2 + 0], gy = g_loc[m * 2 + 1];
    const int grp = tid >> 3, li = tid & 7;

    for (int ca = 0; ca < 256; ca += 32) {
        const int a = ca + grp;
        const bool active = (a < AT);
        const int aa = active ? a : (AT - 1);
        const int azi = aa / 25, ar = aa % 25, ayi = ar / 5, axi = ar % 5;
        const float fx = ((float)axi - 2.0f) * 0.2f + gx;
        const float fy = ((float)ayi - 2.0f) * 0.2f + gy;
        const float fz = (float)azi * 0.22f + 0.1f;
        const float sa = fx * fx + fy * fy + fz * fz;

        float d[16];
        #pragma unroll
        for (int r = 0; r < 16; ++r) {
            int n = li * 16 + r;
            float px = pts[0][n], py = pts[1][n], pz = pts[2][n];
            d[r] = sa - 2.0f * (fx * px + fy * py + fz * pz)
                      + (px * px + py * py + pz * pz);
        }
        int nidx = 0;
        for (int j = 0; j < NSEL; ++j) {
            float best = 1e30f; int bidx = 0;
            #pragma unroll
            for (int r = 0; r < 16; ++r) {
                int n = li * 16 + r;
                if (d[r] < best) { best = d[r]; bidx = n; }
            }
            #pragma unroll
            for (int off = 1; off < 8; off <<= 1) {
                float ov = __shfl_xor(best, off);
                int   oi = __shfl_xor(bidx, off);
                if (ov < best || (ov == best && oi < bidx)) { best = ov; bidx = oi; }
            }
            if (li == j) nidx = bidx;
            if ((bidx >> 4) == li) {
                int slot = bidx & 15;
                #pragma unroll
                for (int r = 0; r < 16; ++r)
                    if (r == slot) d[r] = 1e30f;
            }
        }
        if (active) idxbuf[(m * AT + a) * NSEL + li] = nidx;
    }
}

// ---------------------------------------------------------------- MLP (MFMA L2+L3)
// R21-verbatim (65.5 us measured; LDS 25600 = 6 blocks/CU; anchor-major vox
// stores, one dwordx4 per thread). Measurement control — no changes.
__global__ __launch_bounds__(128) void k_mlpm(
    const float* __restrict__ x, const float* __restrict__ g_loc,
    const int* __restrict__ idxbuf,
    const float* __restrict__ w1, const float* __restrict__ b1,
    const unsigned short* __restrict__ w2m, const float* __restrict__ b2,
    const unsigned short* __restrict__ w3m, const float* __restrict__ b3,
    const float* __restrict__ aw, const float* __restrict__ ab,
    unsigned short* __restrict__ vox, float* __restrict__ attn_out)
{
    const int tid = threadIdx.x;
    const int row0 = blockIdx.x * 128;
    const int row = row0 + tid;

    __shared__ __align__(16) char smem[25600];
    unsigned int*   fbuf = (unsigned int*)smem;              // 8704 B, stride 17 dw
    unsigned int*   f3w  = (unsigned int*)(smem + 8704);     // 16896 B, stride 33 dw
    float*          pts  = (float*)(smem + 8704);            // aliases f3w head
    float*          sbuf = (float*)smem;                     // aliases fbuf head

    const int m0 = row0 / 1800;
    const int m1 = (row0 + 127) / 1800;
    #pragma unroll
    for (int i = tid; i < 640; i += 128) {
        pts[i]       = x[m0 * 640 + i];
        pts[640 + i] = x[m1 * 640 + i];
    }
    __syncthreads();

    // ---- phase A: layer 1 per-thread, pack f1 to fbuf (K 16..31 zeroed) ----
    const int m = row / 1800;
    const int rr = row % 1800;
    const int a = rr >> 3;
    const int base = (m == m0) ? 0 : 640;

    const int azi = a / 25, ar = a % 25, ayi = ar / 5, axi = ar % 5;
    const float gx = g_loc[m * 2 + 0], gy = g_loc[m * 2 + 1];
    const float fx = ((float)axi - 2.0f) * 0.2f + gx;
    const float fy = ((float)ayi - 2.0f) * 0.2f + gy;
    const float fz = (float)azi * 0.22f + 0.1f;

    const int nidx = idxbuf[row];
    const float in0 = pts[base + nidx * 5 + 0] - fx;
    const float in1 = pts[base + nidx * 5 + 1] - fy;
    const float in2 = pts[base + nidx * 5 + 2] - fz;
    const float in3 = pts[base + nidx * 5 + 3];
    const float in4 = pts[base + nidx * 5 + 4];

    float f1v[16];
    #pragma unroll
    for (int j = 0; j < 16; ++j) {
        float s = b1[j];
        s += in0 * w1[0 * 16 + j] + in1 * w1[1 * 16 + j] + in2 * w1[2 * 16 + j]
           + in3 * w1[3 * 16 + j] + in4 * w1[4 * 16 + j];
        f1v[j] = fmaxf(s, 0.0f);
    }
    __syncthreads();   // pts (float) reads complete before f3w (uint) reuse
    #pragma unroll
    for (int kd = 0; kd < 8; ++kd)
        fbuf[tid * 17 + kd] = pk2(f1v[2 * kd], f1v[2 * kd + 1]);
    #pragma unroll
    for (int kd = 8; kd < 16; ++kd)
        fbuf[tid * 17 + kd] = 0u;
    // no barrier: L2 A-frags read only this wave's rows (in-order LDS)

    // ---- phase B: MFMA layers (swapped operands) ----
    const int wv = tid >> 6, lane = tid & 63;
    const int quad = lane >> 4, mcol = lane & 15;

    // layer 2: f2[row][n] for n = nt*16 + quad*4 + reg, row = rowbase + mcol
    bf16x8 w2f[2];
    #pragma unroll
    for (int nt = 0; nt < 2; ++nt) {
        uint4 u = ((const uint4*)w2m)[nt * 64 + lane];
        w2f[nt] = __builtin_bit_cast(bf16x8, u);
    }
    const float4* b24 = (const float4*)b2;
    float4 b2q[2];
    #pragma unroll
    for (int nt = 0; nt < 2; ++nt) b2q[nt] = b24[nt * 4 + quad];

    #pragma unroll
    for (int mt = 0; mt < 4; ++mt) {
        const int rowbase = (wv * 4 + mt) * 16;
        const int abase = (rowbase + mcol) * 17 + quad * 4;
        uint4 au;
        au.x = fbuf[abase + 0]; au.y = fbuf[abase + 1];
        au.z = fbuf[abase + 2]; au.w = fbuf[abase + 3];
        bf16x8 af = __builtin_bit_cast(bf16x8, au);
        #pragma unroll
        for (int nt = 0; nt < 2; ++nt) {
            f32x4 z = (f32x4){0.f, 0.f, 0.f, 0.f};
            f32x4 acc = __builtin_amdgcn_mfma_f32_16x16x32_bf16(w2f[nt], af, z, 0, 0, 0);
            float v0 = fmaxf(acc[0] + b2q[nt].x, 0.0f);
            float v1 = fmaxf(acc[1] + b2q[nt].y, 0.0f);
            float v2 = fmaxf(acc[2] + b2q[nt].z, 0.0f);
            float v3 = fmaxf(acc[3] + b2q[nt].w, 0.0f);
            const int dbase = (rowbase + mcol) * 17 + nt * 8 + quad * 2;
            fbuf[dbase + 0] = pk2(v0, v1);
            fbuf[dbase + 1] = pk2(v2, v3);
        }
    }
    // no barrier: L3 A-frags read only this wave's rows (in-order LDS)

    // layer 3: f3[row][n] for n = nt*16 + quad*4 + reg
    bf16x8 w3f[4];
    #pragma unroll
    for (int nt = 0; nt < 4; ++nt) {
        uint4 u = ((const uint4*)w3m)[nt * 64 + lane];
        w3f[nt] = __builtin_bit_cast(bf16x8, u);
    }
    const float4* b34 = (const float4*)b3;
    float4 b3q[4];
    #pragma unroll
    for (int nt = 0; nt < 4; ++nt) b3q[nt] = b34[nt * 4 + quad];

    #pragma unroll
    for (int mt = 0; mt < 4; ++mt) {
        const int rowbase = (wv * 4 + mt) * 16;
        const int abase = (rowbase + mcol) * 17 + quad * 4;
        uint4 au;
        au.x = fbuf[abase + 0]; au.y = fbuf[abase + 1];
        au.z = fbuf[abase + 2]; au.w = fbuf[abase + 3];
        bf16x8 af = __builtin_bit_cast(bf16x8, au);
        #pragma unroll
        for (int nt = 0; nt < 4; ++nt) {
            f32x4 z = (f32x4){0.f, 0.f, 0.f, 0.f};
            f32x4 acc = __builtin_amdgcn_mfma_f32_16x16x32_bf16(w3f[nt], af, z, 0, 0, 0);
            float v0 = fmaxf(acc[0] + b3q[nt].x, 0.0f);
            float v1 = fmaxf(acc[1] + b3q[nt].y, 0.0f);
            float v2 = fmaxf(acc[2] + b3q[nt].z, 0.0f);
            float v3 = fmaxf(acc[3] + b3q[nt].w, 0.0f);
            const int dbase = (rowbase + mcol) * 33 + nt * 8 + quad * 2;
            f3w[dbase + 0] = pk2(v0, v1);
            f3w[dbase + 1] = pk2(v2, v3);
        }
    }
    // no barrier: phase C reads only this wave's rows (in-order LDS)

    // ---- phase C: score, softmax, weighted sum ----
    const unsigned int* f3dw = (const unsigned int*)f3w;    // row stride 33 dw
    float s0 = 0.f, s1 = 0.f;
    #pragma unroll
    for (int kd = 0; kd < 32; ++kd) {
        unsigned dw = f3dw[tid * 33 + kd];
        s0 = fmaf(__uint_as_float(dw << 16), aw[2 * kd], s0);
        s1 = fmaf(__uint_as_float(dw & 0xFFFF0000u), aw[2 * kd + 1], s1);
    }
    float sc = s0 + s1 + ab[0];

    float mx = sc;
    #pragma unroll
    for (int off = 1; off < 8; off <<= 1) mx = fmaxf(mx, __shfl_xor(mx, off));
    float e = expf(sc - mx);
    float den = e;
    #pragma unroll
    for (int off = 1; off < 8; off <<= 1) den += __shfl_xor(den, off);
    const float at = e / den;
    attn_out[row] = at;

    // lane li owns h = q*16 + li*2 + {0,1}  (conflict-free b32 reads)
    const int lgrp = tid >> 3;
    const int li = tid & 7;
    const int wl = tid & 63;
    float oo[8];
    #pragma unroll
    for (int i = 0; i < 8; ++i) oo[i] = 0.0f;
    #pragma unroll
    for (int ns = 0; ns < 8; ++ns) {
        float atn = __shfl(at, (wl >> 3) * 8 + ns);
        const int rbase = (lgrp * 8 + ns) * 33;
        #pragma unroll
        for (int q = 0; q < 4; ++q) {
            unsigned dw = f3dw[rbase + q * 8 + li];
            oo[2 * q + 0] = fmaf(atn, __uint_as_float(dw << 16), oo[2 * q + 0]);
            oo[2 * q + 1] = fmaf(atn, __uint_as_float(dw & 0xFFFF0000u), oo[2 * q + 1]);
        }
    }
    __syncthreads();   // fence: cross-wave fbuf loads done -> sbuf (alias) writes
    #pragma unroll
    for (int q = 0; q < 4; ++q) {
        sbuf[lgrp * 65 + q * 16 + li * 2 + 0] = oo[2 * q + 0];
        sbuf[lgrp * 65 + q * 16 + li * 2 + 1] = oo[2 * q + 1];
    }
    __syncthreads();   // fence: cross-wave sbuf reads below

    const int al = tid & 15, j = tid >> 4;
    const int ga = (row0 >> 3) + al;
    const int ma = ga / 225, aa2 = ga % 225;
    const int hb = j * 8;
    {
        unsigned p0 = pk2(sbuf[al * 65 + hb + 0], sbuf[al * 65 + hb + 1]);
        unsigned p1 = pk2(sbuf[al * 65 + hb + 2], sbuf[al * 65 + hb + 3]);
        unsigned p2 = pk2(sbuf[al * 65 + hb + 4], sbuf[al * 65 + hb + 5]);
        unsigned p3 = pk2(sbuf[al * 65 + hb + 6], sbuf[al * 65 + hb + 7]);
        uint4 st; st.x = p0; st.y = p1; st.z = p2; st.w = p3;
        // vox[m][aa][h]: 16B-aligned ((ma*225+aa2)*64 + hb is mult of 8 us)
        *(uint4*)(vox + ((size_t)(ma * 225 + aa2) * 64 + hb)) = st;
    }
}

// ---------------------------------------------------------------- conv1 MFMA
// R23: reverted to R21's TWO images per block (grid 512) — R22's 1-img
// split doubled per-CU A-load L1 traffic (+15 us, kernel is A-load-bound).
// Anchor-major vox staging decode (R21). Barrier every 4 K-steps aligns
// waves for L1 A-reuse.
__global__ __launch_bounds__(256) void k_conv1m(
    const unsigned short* __restrict__ vox, const unsigned short* __restrict__ w1m,
    const float* __restrict__ b1, unsigned short* __restrict__ out)
{
    const int m0 = blockIdx.x * 2;
    const int tid = threadIdx.x;
    __shared__ unsigned short voxT[2][225 * 66];

    #pragma unroll
    for (int img = 0; img < 2; ++img) {
        const unsigned int* vsrc =
            (const unsigned int*)(vox + (size_t)(m0 + img) * 14400);
        for (int i = tid; i < 7200; i += 256) {
            unsigned v = vsrc[i];
            int a0 = i >> 5;              // 32 dws (64 ch) per anchor
            int c2 = (i & 31) * 2;        // even channel
            *(unsigned*)(&voxT[img][a0 * 66 + c2]) = v;   // 4B-aligned
        }
    }
    __syncthreads();

    const int wv = tid >> 6, lane = tid & 63;
    const int quad = lane >> 4, n = lane & 15;
    const int p = wv * 16 + n;
    const int pe = (p > 62) ? 62 : p;
    const int zo = pe / 9, pr = pe % 9, yo = pr / 3, xo = pr % 3;
    const int basep = zo * 25 + yo * 5 + xo;

    f32x4 acc[2][6];
    #pragma unroll
    for (int g = 0; g < 2; ++g)
        #pragma unroll
        for (int t = 0; t < 6; ++t) acc[g][t] = (f32x4){0.f, 0.f, 0.f, 0.f};

    const uint4* Aptr = (const uint4*)w1m;

    auto loadB = [&](int img, int s) -> uint4 {
        int tap = s >> 1;
        int dz = tap / 9, tr = tap % 9, dy = tr / 3, dx = tr % 3;
        int rw = basep + dz * 25 + dy * 5 + dx;
        int bidx = rw * 66 + (s & 1) * 32 + quad * 8;
        const unsigned int* vp = (const unsigned int*)(&voxT[img][0] + bidx);
        uint4 r; r.x = vp[0]; r.y = vp[1]; r.z = vp[2]; r.w = vp[3];
        return r;
    };

    uint4 Acur[6], Anxt[6];
    uint4 Bcur[2], Bnxt[2];
    #pragma unroll
    for (int t = 0; t < 6; ++t) Acur[t] = Aptr[t * 64 + lane];
    Bcur[0] = loadB(0, 0); Bcur[1] = loadB(1, 0);

    for (int s = 0; s < 54; ++s) {
        if ((s & 3) == 0) __syncthreads();   // align waves for L1 A-reuse
        if (s < 53) {
            Bnxt[0] = loadB(0, s + 1);
            Bnxt[1] = loadB(1, s + 1);
            #pragma unroll
            for (int t = 0; t < 6; ++t)
                Anxt[t] = Aptr[((s + 1) * 6 + t) * 64 + lane];
        }
        bf16x8 bf0 = __builtin_bit_cast(bf16x8, Bcur[0]);
        bf16x8 bf1 = __builtin_bit_cast(bf16x8, Bcur[1]);
        #pragma unroll
        for (int t = 0; t < 6; ++t) {
            bf16x8 af = __builtin_bit_cast(bf16x8, Acur[t]);
            acc[0][t] = __builtin_amdgcn_mfma_f32_16x16x32_bf16(af, bf0, acc[0][t], 0, 0, 0);
            acc[1][t] = __builtin_amdgcn_mfma_f32_16x16x32_bf16(af, bf1, acc[1][t], 0, 0, 0);
        }
        #pragma unroll
        for (int t = 0; t < 6; ++t) Acur[t] = Anxt[t];
        Bcur[0] = Bnxt[0]; Bcur[1] = Bnxt[1];
    }

    if (p < 63) {
        #pragma unroll
        for (int g = 0; g < 2; ++g) {
            #pragma unroll
            for (int t = 0; t < 6; ++t) {
                #pragma unroll
                for (int r = 0; r < 4; r += 2) {
                    int o = t * 16 + quad * 4 + r;
                    unsigned pk = pk2(fmaxf(acc[g][t][r] + b1[o], 0.0f),
                                      fmaxf(acc[g][t][r + 1] + b1[o + 1], 0.0f));
                    out[(m0 + g) * (96 * 63) + o * 63 + p]       = (unsigned short)pk;
                    out[(m0 + g) * (96 * 63) + (o + 1) * 63 + p] = (unsigned short)(pk >> 16);
                }
            }
        }
    }
}

// ---------------------------------------------------------------- conv2 + conv3 + xwi
// conv2 MFMA as R10 (2 images/block). R22's register B-prefetch RETAINED
// (bit-identical; this round attributes its isolated effect with conv1m
// reverted). conv3 + xwi: R10 exact summation order; w3t coalesced.
__global__ __launch_bounds__(256) void k_c23(
    const unsigned short* __restrict__ c1, const unsigned short* __restrict__ w2n,
    const float* __restrict__ b2, const float* __restrict__ w3t,
    const float* __restrict__ b3, const float* __restrict__ wi,
    const float* __restrict__ lb, float* __restrict__ xwi)
{
    const int tid = threadIdx.x;
    const int m0 = blockIdx.x * 2;
    __shared__ unsigned short c1T[2 * 63 * C2S];   // 24696 B
    __shared__ float c2l[2][640];                  // 5120 B
    __shared__ float part[2][4][64];               // 2048 B
    __shared__ float vvl[2][64];                   // 512 B

    const unsigned int* csrc = (const unsigned int*)(c1 + (size_t)m0 * 6048);
    for (int i = tid; i < 6048; i += 256) {
        unsigned v = csrc[i];
        int e0 = 2 * i;
        int mi = (i >= 3024);
        int r0 = e0 - mi * 6048, r1 = r0 + 1;
        int o0 = r0 / 63, p0 = r0 - o0 * 63;
        int o1 = r1 / 63, p1 = r1 - o1 * 63;
        c1T[(mi * 63 + p0) * C2S + o0] = (unsigned short)(v & 0xFFFFu);
        c1T[(mi * 63 + p1) * C2S + o1] = (unsigned short)(v >> 16);
    }
    __syncthreads();

    const int wv = tid >> 6, lane = tid & 63;
    const int quad = lane >> 4, ncol = lane & 15;
    const int arow = lane & 15;
    const int mi = (arow < 10) ? arow / 5 : 1;
    const int zo = (arow < 10) ? arow % 5 : 4;

    f32x4 acc[2];
    acc[0] = (f32x4){0.f, 0.f, 0.f, 0.f};
    acc[1] = (f32x4){0.f, 0.f, 0.f, 0.f};
    const uint4* Bptr = (const uint4*)w2n;

    uint4 Bc[2], Bn[2];
    Bc[0] = Bptr[(wv * 2 + 0) * 64 + lane];
    Bc[1] = Bptr[(wv * 2 + 1) * 64 + lane];

    for (int tap = 0; tap < 27; ++tap) {
        const int dz = tap / 9, r9 = tap % 9;
        const int rowb = (mi * 63 + (zo + dz) * 9 + r9) * C2S;
        #pragma unroll
        for (int sub = 0; sub < 3; ++sub) {
            const int s = tap * 3 + sub;
            const unsigned int* ap =
                (const unsigned int*)(c1T + rowb + sub * 32 + quad * 8);
            uint4 au; au.x = ap[0]; au.y = ap[1]; au.z = ap[2]; au.w = ap[3];
            bf16x8 af = __builtin_bit_cast(bf16x8, au);
            if (s < 80) {
                Bn[0] = Bptr[((s + 1) * 8 + wv * 2 + 0) * 64 + lane];
                Bn[1] = Bptr[((s + 1) * 8 + wv * 2 + 1) * 64 + lane];
            }
            #pragma unroll
            for (int nt = 0; nt < 2; ++nt) {
                bf16x8 bf = __builtin_bit_cast(bf16x8, Bc[nt]);
                acc[nt] = __builtin_amdgcn_mfma_f32_16x16x32_bf16(af, bf, acc[nt], 0, 0, 0);
            }
            Bc[0] = Bn[0]; Bc[1] = Bn[1];
        }
    }

    #pragma unroll
    for (int nt = 0; nt < 2; ++nt) {
        const int o = (wv * 2 + nt) * 16 + ncol;
        const float bias = b2[o];
        #pragma unroll
        for (int reg = 0; reg < 4; ++reg) {
            int rr = quad * 4 + reg;
            if (rr < 10)
                c2l[rr / 5][o * 5 + (rr % 5)] = fmaxf(acc[nt][reg] + bias, 0.0f);
        }
    }
    __syncthreads();

    // conv3: R10 order — per image, 4 partials of 160 K each (u=tid&63,
    // kq=tid>>6), sequential fmaf chain, unroll 8.
    {
        const int u = tid & 63, kq = tid >> 6;
        const int k0 = kq * 160;
        #pragma unroll
        for (int mi2 = 0; mi2 < 2; ++mi2) {
            float acc3 = 0.0f;
            #pragma unroll 8
            for (int k = k0; k < k0 + 160; ++k)
                acc3 = fmaf(c2l[mi2][k], w3t[k * 64 + u], acc3);
            part[mi2][kq][u] = acc3;
        }
    }
    __syncthreads();
    if (tid < 128) {
        int mi2 = tid >> 6, u = tid & 63;
        vvl[mi2][u] = b3[u] + ((part[mi2][0][u] + part[mi2][1][u])
                    + (part[mi2][2][u] + part[mi2][3][u]));
    }
    __syncthreads();

    // xwi: R10 order — sequential k 0..63
    #pragma unroll
    for (int mi2 = 0; mi2 < 2; ++mi2) {
        float a2 = lb[tid];
        #pragma unroll
        for (int k = 0; k < 64; ++k)
            a2 = fmaf(vvl[mi2][k], wi[k * 256 + tid], a2);
        xwi[(m0 + mi2) * 256 + tid] = a2;
    }
}

// ---------------------------------------------------------------- LSTM
// R12: software-pipeline the xwi load one step ahead so its global-load
// latency hides under the 64-FMA recurrent dot (values identical).
__global__ __launch_bounds__(256) void k_lstm(
    const float* __restrict__ xwi, const float* __restrict__ whg,
    const float* __restrict__ h0, const float* __restrict__ c0,
    float* __restrict__ avec, float* __restrict__ hn, float* __restrict__ cn)
{
    const int b = blockIdx.x;
    const int j = threadIdx.x;
    __shared__ __align__(16) float hbuf[64];
    __shared__ float gbuf[256];

    float wh[64];
    #pragma unroll
    for (int k = 0; k < 64; ++k) wh[k] = whg[k * 256 + j];

    if (j < 64) hbuf[j] = h0[b * 64 + j];
    float c = (j < 64) ? c0[b * 64 + j] : 0.0f;
    const bool is_tanh_gate = ((j >> 6) == 2);
    __syncthreads();

    const float4* hb4 = (const float4*)hbuf;
    float xt = xwi[(b * 64 + 0) * 256 + j];
    for (int t = 0; t < 64; ++t) {
        float xt_next = (t < 63) ? xwi[(b * 64 + t + 1) * 256 + j] : 0.0f;
        float g = xt;
        float p[4] = {0.f, 0.f, 0.f, 0.f};
        #pragma unroll
        for (int k4 = 0; k4 < 16; ++k4) {
            float4 h4 = hb4[k4];
            int q = k4 & 3;
            p[q] = fmaf(h4.x, wh[4 * k4 + 0], p[q]);
            p[q] = fmaf(h4.y, wh[4 * k4 + 1], p[q]);
            p[q] = fmaf(h4.z, wh[4 * k4 + 2], p[q]);
            p[q] = fmaf(h4.w, wh[4 * k4 + 3], p[q]);
        }
        g += (p[0] + p[1]) + (p[2] + p[3]);
        gbuf[j] = is_tanh_gate ? tanhf(g) : sigm(g);
        __syncthreads();
        if (j < 64) {
            c = gbuf[64 + j] * c + gbuf[j] * gbuf[128 + j];
            float h = gbuf[192 + j] * tanhf(c);
            hbuf[j] = h;
            avec[(b * 64 + t) * 64 + j] = h;
        }
        __syncthreads();
        xt = xt_next;
    }
    if (j < 64) {
        hn[b * 64 + j] = hbuf[j];
        cn[b * 64 + j] = c;
    }
}

// ---------------------------------------------------------------- launch
extern "C" void kernel_launch(void* const* d_in, const int* in_sizes, int n_in,
                              void* d_out, int out_size, void* d_ws, size_t ws_size,
                              hipStream_t stream) {
    const float* x     = (const float*)d_in[0];
    const float* g_loc = (const float*)d_in[1];
    const float* h0    = (const float*)d_in[2];
    const float* c0    = (const float*)d_in[3];
    const float* pn_w1 = (const float*)d_in[4];
    const float* pn_b1 = (const float*)d_in[5];
    const float* pn_w2 = (const float*)d_in[6];
    const float* pn_b2 = (const float*)d_in[7];
    const float* pn_w3 = (const float*)d_in[8];
    const float* pn_b3 = (const float*)d_in[9];
    const float* aw    = (const float*)d_in[10];
    const float* ab    = (const float*)d_in[11];
    const float* vx_w1 = (const float*)d_in[12];
    const float* vx_b1 = (const float*)d_in[13];
    const float* vx_w2 = (const float*)d_in[14];
    const float* vx_b2 = (const float*)d_in[15];
    const float* vx_w3 = (const float*)d_in[16];
    const float* vx_b3 = (const float*)d_in[17];
    const float* lwi   = (const float*)d_in[18];
    const float* lwh   = (const float*)d_in[19];
    const float* lb    = (const float*)d_in[20];

    float* ws  = (float*)d_ws;
    float* voxr = ws;
    float* c1r  = voxr + SZ_VOX;
    float* c2  = c1r + SZ_C1;         // unused (c2 in LDS; layout stability)
    float* vv  = c2 + SZ_C2;          // unused
    float* xwi = vv + SZ_VV;
    float* w1r = xwi + SZ_XWI;
    float* w2r = w1r + SZ_W1T;
    float* w3t = w2r + SZ_W2T;
    float* w2mr = w3t + SZ_W3T;
    unsigned short* voxh = (unsigned short*)voxr;
    unsigned short* c1h  = (unsigned short*)c1r;
    unsigned short* w1m = (unsigned short*)w1r;
    unsigned short* w2n = (unsigned short*)w2r;
    unsigned short* w2m = (unsigned short*)w2mr;
    unsigned short* w3m = (unsigned short*)xwi;  // aliases xwi head; xwi written later
    int*   idxb = (int*)c1r;          // idx lives in the (not-yet-written) c1 region

    float* out   = (float*)d_out;
    float* avec  = out;                   // 65536
    float* attnw = out + 65536;           // 1843200
    float* hn    = out + 65536 + 1843200; // 1024
    float* cn    = hn + 1024;             // 1024

    k_transpose<<<405, 256, 0, stream>>>(vx_w1, vx_w2, vx_w3, pn_w3, pn_w2,
                                         w1m, w2n, w3t, w3m, w2m);
    k_group<<<1024, 256, 0, stream>>>(x, g_loc, idxb);
    k_mlpm<<<14400, 128, 0, stream>>>(x, g_loc, idxb, pn_w1, pn_b1, w2m, pn_b2,
                                      w3m, pn_b3, aw, ab, voxh, attnw);
    k_conv1m<<<512, 256, 0, stream>>>(voxh, w1m, vx_b1, c1h);
    k_c23<<<512, 256, 0, stream>>>(c1h, w2n, vx_b2, w3t, vx_b3, lwi, lb, xwi);
    k_lstm<<<16, 256, 0, stream>>>(xwi, lwh, h0, c0, avec, hn, cn);
}

// Round 13
// 317.735 us; speedup vs baseline: 1.0808x; 1.0274x over previous
//
#include <hip/hip_runtime.h>
#include <cmath>

// Shapes (fixed by the problem)
#define AT 225      // Z*Y*X anchors
#define NP 128      // points per sample
#define MT 1024     // B*T
#define NSEL 8
#define HD 64

// workspace float offsets
#define SZ_VOX  (1024u*64u*225u)     // region sized in floats; holds bf16 vox [m][aa][h] (R21)
#define SZ_C1   (1024u*96u*63u)      // region holds bf16 c1 (idx aliases head before conv1)
#define SZ_C2   (1024u*128u*5u)      // unused (c2 lives in LDS now)
#define SZ_VV   (1024u*64u)
#define SZ_XWI  (1024u*256u)         // (w3m aliases its head before k_c23 runs)
#define SZ_W1T  (64u*27u*96u)        // holds w1m (bf16 A-frags, conv1)
#define SZ_W2T  (96u*27u*128u)       // holds w2n (bf16 B-frags, conv2)
#define SZ_W3T  (640u*64u)           // w3t (coalesced conv3 weights)
#define SZ_W2M  (512u)               // pn layer2 B-frags (128 uint4)

#define C2S 98                       // conv2 LDS row stride (us), 49 dw (odd)

typedef __attribute__((ext_vector_type(8))) short bf16x8;
typedef __attribute__((ext_vector_type(4))) float f32x4;

__device__ __forceinline__ float sigm(float x) { return 1.0f / (1.0f + expf(-x)); }

__device__ __forceinline__ unsigned short f2bf(float f) {
    unsigned u = __float_as_uint(f);
    unsigned r = u + 0x7FFF + ((u >> 16) & 1);   // RNE
    return (unsigned short)(r >> 16);
}

// R15: real packed bf16 convert (single v_cvt_pk_bf16_f32; no builtin exists).
// NOTE (R16): v_fma_mix_f32_bf16 does NOT exist on gfx950. Do not retry.
// NOTE (R18): for GLOBAL memory, coalescing beats instruction count.
// NOTE (R20/R24): k_mlpm LDS granule boundaries are decisive — 27136 B cost
// a block/CU (8%); R24 shrinks 25600 -> 16896 B (6 -> 9 blocks/CU).
// NOTE (R22): k_conv1m is A-load L1-BW bound — keep 2 images/block.
__device__ __forceinline__ unsigned pk2(float a, float b) {
    unsigned r;
    asm("v_cvt_pk_bf16_f32 %0, %1, %2" : "=v"(r) : "v"(a), "v"(b));
    return r;
}

// ---------------------------------------------------------------- transpose
__global__ __launch_bounds__(256) void k_transpose(
    const float* __restrict__ w1, const float* __restrict__ w2,
    const float* __restrict__ w3, const float* __restrict__ pnw3,
    const float* __restrict__ pnw2,
    unsigned short* __restrict__ w1m, unsigned short* __restrict__ w2n,
    float* __restrict__ w3t, unsigned short* __restrict__ w3m,
    unsigned short* __restrict__ w2m)
{
    int idx = blockIdx.x * 256 + threadIdx.x;
    if (idx < 20736) {
        int lane = idx & 63, r = idx >> 6;
        int t = r % 6, s = r / 6;
        int o = t * 16 + (lane & 15);
        int kb = s * 32 + (lane >> 4) * 8;
        unsigned int dw[4];
        #pragma unroll
        for (int jd = 0; jd < 4; ++jd) {
            int k0 = kb + 2 * jd, k1 = k0 + 1;
            dw[jd] = (unsigned)f2bf(w1[o * 1728 + (k0 & 63) * 27 + (k0 >> 6)]) |
                     ((unsigned)f2bf(w1[o * 1728 + (k1 & 63) * 27 + (k1 >> 6)]) << 16);
        }
        uint4 v; v.x = dw[0]; v.y = dw[1]; v.z = dw[2]; v.w = dw[3];
        ((uint4*)w1m)[idx] = v;
    } else if (idx < 62208) {
        int q = idx - 20736;
        int lane = q & 63, r = q >> 6;
        int nt = r & 7, s = r >> 3;
        int o = nt * 16 + (lane & 15);
        int kb = s * 32 + (lane >> 4) * 8;
        unsigned int dw[4];
        #pragma unroll
        for (int jd = 0; jd < 4; ++jd) {
            int k0 = kb + 2 * jd, k1 = k0 + 1;
            dw[jd] = (unsigned)f2bf(w2[o * 2592 + (k0 % 96) * 27 + (k0 / 96)]) |
                     ((unsigned)f2bf(w2[o * 2592 + (k1 % 96) * 27 + (k1 / 96)]) << 16);
        }
        uint4 v; v.x = dw[0]; v.y = dw[1]; v.z = dw[2]; v.w = dw[3];
        ((uint4*)w2n)[q] = v;
    } else if (idx < 103168) {
        int k = idx - 62208;
        int u = k & 63, r = k >> 6;
        w3t[k] = w3[u * 640 + r];
    } else if (idx < 103424) {
        int k = idx - 103168;
        int lane = k & 63, nt = k >> 6;
        int n = nt * 16 + (lane & 15);
        int kb = (lane >> 4) * 8;
        unsigned int dw[4];
        #pragma unroll
        for (int jd = 0; jd < 4; ++jd) {
            int k0 = kb + 2 * jd;
            dw[jd] = (unsigned)f2bf(pnw3[k0 * 64 + n]) |
                     ((unsigned)f2bf(pnw3[(k0 + 1) * 64 + n]) << 16);
        }
        uint4 v; v.x = dw[0]; v.y = dw[1]; v.z = dw[2]; v.w = dw[3];
        ((uint4*)w3m)[k] = v;
    } else if (idx < 103552) {
        int k = idx - 103424;
        int lane = k & 63, nt = k >> 6;          // nt 0..1
        int n = nt * 16 + (lane & 15);
        int kb = (lane >> 4) * 8;
        unsigned int dw[4];
        #pragma unroll
        for (int jd = 0; jd < 4; ++jd) {
            int k0 = kb + 2 * jd, k1 = k0 + 1;
            float a = (k0 < 16) ? pnw2[k0 * 32 + n] : 0.0f;
            float b = (k1 < 16) ? pnw2[k1 * 32 + n] : 0.0f;
            dw[jd] = (unsigned)f2bf(a) | ((unsigned)f2bf(b) << 16);
        }
        uint4 v; v.x = dw[0]; v.y = dw[1]; v.z = dw[2]; v.w = dw[3];
        ((uint4*)w2m)[k] = v;
    }
}

// ---------------------------------------------------------------- grouping
// R10-verbatim: selection codegen is bit-stable in THIS compilation context;
// fusing it elsewhere changed FMA contraction and flipped near-tie neighbor
// picks (R11 failure). Do not merge into k_mlpm.
// R22 measurement: ~65 us, VALUBusy ~69%, HBM 1.7% — issue-bound near its
// SIMD floor. Leave as is.
__global__ __launch_bounds__(256) void k_group(
    const float* __restrict__ x, const float* __restrict__ g_loc,
    int* __restrict__ idxbuf)
{
    const int m = blockIdx.x;
    const int tid = threadIdx.x;
    __shared__ float pts[3][NP];

    for (int idx = tid; idx < NP * 5; idx += 256) {
        int n = idx / 5, c = idx % 5;
        if (c < 3) pts[c][n] = x[m * (NP * 5) + idx];
    }
    __syncthreads();

    const float gx = g_loc[m * 2 + 0], gy = g_loc[m * 2 + 1];
    const int grp = tid >> 3, li = tid & 7;

    for (int ca = 0; ca < 256; ca += 32) {
        const int a = ca + grp;
        const bool active = (a < AT);
        const int aa = active ? a : (AT - 1);
        const int azi = aa / 25, ar = aa % 25, ayi = ar / 5, axi = ar % 5;
        const float fx = ((float)axi - 2.0f) * 0.2f + gx;
        const float fy = ((float)ayi - 2.0f) * 0.2f + gy;
        const float fz = (float)azi * 0.22f + 0.1f;
        const float sa = fx * fx + fy * fy + fz * fz;

        float d[16];
        #pragma unroll
        for (int r = 0; r < 16; ++r) {
            int n = li * 16 + r;
            float px = pts[0][n], py = pts[1][n], pz = pts[2][n];
            d[r] = sa - 2.0f * (fx * px + fy * py + fz * pz)
                      + (px * px + py * py + pz * pz);
        }
        int nidx = 0;
        for (int j = 0; j < NSEL; ++j) {
            float best = 1e30f; int bidx = 0;
            #pragma unroll
            for (int r = 0; r < 16; ++r) {
                int n = li * 16 + r;
                if (d[r] < best) { best = d[r]; bidx = n; }
            }
            #pragma unroll
            for (int off = 1; off < 8; off <<= 1) {
                float ov = __shfl_xor(best, off);
                int   oi = __shfl_xor(bidx, off);
                if (ov < best || (ov == best && oi < bidx)) { best = ov; bidx = oi; }
            }
            if (li == j) nidx = bidx;
            if ((bidx >> 4) == li) {
                int slot = bidx & 15;
                #pragma unroll
                for (int r = 0; r < 16; ++r)
                    if (r == slot) d[r] = 1e30f;
            }
        }
        if (active) idxbuf[(m * AT + a) * NSEL + li] = nidx;
    }
}

// ---------------------------------------------------------------- MLP (MFMA L2+L3)
// R24: f3 fully ALIASES fbuf — LDS 25600 -> 16896 B (6 -> 9 blocks/CU,
// 12 -> 18 waves/CU). Enabler: each wave hoists ALL 4 of its L3 A-frags
// into registers (4x uint4, +12 VGPR) before any f3 store; one new
// __syncthreads() fences cross-wave fbuf-read -> f3-write overlap (wave 0's
// f3 rows 33-63 overlap wave 1's fbuf region). Values bit-identical.
// All regions alias offset 0, barrier-separated:
//   pts 5120 B -> fbuf 8704 B (stride 17 dw) -> f3w 16896 B (stride 33 dw)
//   -> sbuf 4160 B
__global__ __launch_bounds__(128) void k_mlpm(
    const float* __restrict__ x, const float* __restrict__ g_loc,
    const int* __restrict__ idxbuf,
    const float* __restrict__ w1, const float* __restrict__ b1,
    const unsigned short* __restrict__ w2m, const float* __restrict__ b2,
    const unsigned short* __restrict__ w3m, const float* __restrict__ b3,
    const float* __restrict__ aw, const float* __restrict__ ab,
    unsigned short* __restrict__ vox, float* __restrict__ attn_out)
{
    const int tid = threadIdx.x;
    const int row0 = blockIdx.x * 128;
    const int row = row0 + tid;

    __shared__ __align__(16) char smem[16896];
    unsigned int*   fbuf = (unsigned int*)smem;   // stride 17 dw (f1 then f2)
    unsigned int*   f3w  = (unsigned int*)smem;   // stride 33 dw (aliases fbuf)
    float*          pts  = (float*)smem;          // 1280 f32 (aliases head)
    float*          sbuf = (float*)smem;          // 16x65 f32 (aliases head)

    const int m0 = row0 / 1800;
    const int m1 = (row0 + 127) / 1800;
    #pragma unroll
    for (int i = tid; i < 640; i += 128) {
        pts[i]       = x[m0 * 640 + i];
        pts[640 + i] = x[m1 * 640 + i];
    }
    __syncthreads();

    // ---- phase A: layer 1 per-thread, pack f1 to fbuf (K 16..31 zeroed) ----
    const int m = row / 1800;
    const int rr = row % 1800;
    const int a = rr >> 3;
    const int base = (m == m0) ? 0 : 640;

    const int azi = a / 25, ar = a % 25, ayi = ar / 5, axi = ar % 5;
    const float gx = g_loc[m * 2 + 0], gy = g_loc[m * 2 + 1];
    const float fx = ((float)axi - 2.0f) * 0.2f + gx;
    const float fy = ((float)ayi - 2.0f) * 0.2f + gy;
    const float fz = (float)azi * 0.22f + 0.1f;

    const int nidx = idxbuf[row];
    const float in0 = pts[base + nidx * 5 + 0] - fx;
    const float in1 = pts[base + nidx * 5 + 1] - fy;
    const float in2 = pts[base + nidx * 5 + 2] - fz;
    const float in3 = pts[base + nidx * 5 + 3];
    const float in4 = pts[base + nidx * 5 + 4];

    float f1v[16];
    #pragma unroll
    for (int j = 0; j < 16; ++j) {
        float s = b1[j];
        s += in0 * w1[0 * 16 + j] + in1 * w1[1 * 16 + j] + in2 * w1[2 * 16 + j]
           + in3 * w1[3 * 16 + j] + in4 * w1[4 * 16 + j];
        f1v[j] = fmaxf(s, 0.0f);
    }
    __syncthreads();   // all pts (float) reads complete before fbuf writes (alias)
    #pragma unroll
    for (int kd = 0; kd < 8; ++kd)
        fbuf[tid * 17 + kd] = pk2(f1v[2 * kd], f1v[2 * kd + 1]);
    #pragma unroll
    for (int kd = 8; kd < 16; ++kd)
        fbuf[tid * 17 + kd] = 0u;
    // no barrier: L2 A-frags read only this wave's rows (in-order LDS)

    // ---- phase B: MFMA layers (swapped operands) ----
    const int wv = tid >> 6, lane = tid & 63;
    const int quad = lane >> 4, mcol = lane & 15;

    // layer 2: f2[row][n] for n = nt*16 + quad*4 + reg, row = rowbase + mcol
    bf16x8 w2f[2];
    #pragma unroll
    for (int nt = 0; nt < 2; ++nt) {
        uint4 u = ((const uint4*)w2m)[nt * 64 + lane];
        w2f[nt] = __builtin_bit_cast(bf16x8, u);
    }
    const float4* b24 = (const float4*)b2;
    float4 b2q[2];
    #pragma unroll
    for (int nt = 0; nt < 2; ++nt) b2q[nt] = b24[nt * 4 + quad];

    #pragma unroll
    for (int mt = 0; mt < 4; ++mt) {
        const int rowbase = (wv * 4 + mt) * 16;
        const int abase = (rowbase + mcol) * 17 + quad * 4;
        uint4 au;
        au.x = fbuf[abase + 0]; au.y = fbuf[abase + 1];
        au.z = fbuf[abase + 2]; au.w = fbuf[abase + 3];
        bf16x8 af = __builtin_bit_cast(bf16x8, au);
        #pragma unroll
        for (int nt = 0; nt < 2; ++nt) {
            f32x4 z = (f32x4){0.f, 0.f, 0.f, 0.f};
            f32x4 acc = __builtin_amdgcn_mfma_f32_16x16x32_bf16(w2f[nt], af, z, 0, 0, 0);
            float v0 = fmaxf(acc[0] + b2q[nt].x, 0.0f);
            float v1 = fmaxf(acc[1] + b2q[nt].y, 0.0f);
            float v2 = fmaxf(acc[2] + b2q[nt].z, 0.0f);
            float v3 = fmaxf(acc[3] + b2q[nt].w, 0.0f);
            const int dbase = (rowbase + mcol) * 17 + nt * 8 + quad * 2;
            fbuf[dbase + 0] = pk2(v0, v1);
            fbuf[dbase + 1] = pk2(v2, v3);
        }
    }
    // no barrier: L3 A-frag preload reads only this wave's rows (in-order LDS)

    // layer 3: preload ALL 4 tiles' A-frags, then barrier, then MFMA + f3
    // stores (f3 aliases fbuf; cross-wave overlap fenced by the barrier).
    uint4 aA[4];
    #pragma unroll
    for (int mt = 0; mt < 4; ++mt) {
        const int abase = ((wv * 4 + mt) * 16 + mcol) * 17 + quad * 4;
        aA[mt].x = fbuf[abase + 0]; aA[mt].y = fbuf[abase + 1];
        aA[mt].z = fbuf[abase + 2]; aA[mt].w = fbuf[abase + 3];
    }

    bf16x8 w3f[4];
    #pragma unroll
    for (int nt = 0; nt < 4; ++nt) {
        uint4 u = ((const uint4*)w3m)[nt * 64 + lane];
        w3f[nt] = __builtin_bit_cast(bf16x8, u);
    }
    const float4* b34 = (const float4*)b3;
    float4 b3q[4];
    #pragma unroll
    for (int nt = 0; nt < 4; ++nt) b3q[nt] = b34[nt * 4 + quad];

    __syncthreads();   // NEW fence: all waves' fbuf reads done -> f3 (alias) writes

    #pragma unroll
    for (int mt = 0; mt < 4; ++mt) {
        const int rowbase = (wv * 4 + mt) * 16;
        bf16x8 af = __builtin_bit_cast(bf16x8, aA[mt]);
        #pragma unroll
        for (int nt = 0; nt < 4; ++nt) {
            f32x4 z = (f32x4){0.f, 0.f, 0.f, 0.f};
            f32x4 acc = __builtin_amdgcn_mfma_f32_16x16x32_bf16(w3f[nt], af, z, 0, 0, 0);
            float v0 = fmaxf(acc[0] + b3q[nt].x, 0.0f);
            float v1 = fmaxf(acc[1] + b3q[nt].y, 0.0f);
            float v2 = fmaxf(acc[2] + b3q[nt].z, 0.0f);
            float v3 = fmaxf(acc[3] + b3q[nt].w, 0.0f);
            const int dbase = (rowbase + mcol) * 33 + nt * 8 + quad * 2;
            f3w[dbase + 0] = pk2(v0, v1);
            f3w[dbase + 1] = pk2(v2, v3);
        }
    }
    // no barrier: phase C reads only this wave's rows (in-order LDS)

    // ---- phase C: score, softmax, weighted sum ----
    const unsigned int* f3dw = (const unsigned int*)f3w;    // row stride 33 dw
    float s0 = 0.f, s1 = 0.f;
    #pragma unroll
    for (int kd = 0; kd < 32; ++kd) {
        unsigned dw = f3dw[tid * 33 + kd];
        s0 = fmaf(__uint_as_float(dw << 16), aw[2 * kd], s0);
        s1 = fmaf(__uint_as_float(dw & 0xFFFF0000u), aw[2 * kd + 1], s1);
    }
    float sc = s0 + s1 + ab[0];

    float mx = sc;
    #pragma unroll
    for (int off = 1; off < 8; off <<= 1) mx = fmaxf(mx, __shfl_xor(mx, off));
    float e = expf(sc - mx);
    float den = e;
    #pragma unroll
    for (int off = 1; off < 8; off <<= 1) den += __shfl_xor(den, off);
    const float at = e / den;
    attn_out[row] = at;

    // lane li owns h = q*16 + li*2 + {0,1}  (conflict-free b32 reads)
    const int lgrp = tid >> 3;
    const int li = tid & 7;
    const int wl = tid & 63;
    float oo[8];
    #pragma unroll
    for (int i = 0; i < 8; ++i) oo[i] = 0.0f;
    #pragma unroll
    for (int ns = 0; ns < 8; ++ns) {
        float atn = __shfl(at, (wl >> 3) * 8 + ns);
        const int rbase = (lgrp * 8 + ns) * 33;
        #pragma unroll
        for (int q = 0; q < 4; ++q) {
            unsigned dw = f3dw[rbase + q * 8 + li];
            oo[2 * q + 0] = fmaf(atn, __uint_as_float(dw << 16), oo[2 * q + 0]);
            oo[2 * q + 1] = fmaf(atn, __uint_as_float(dw & 0xFFFF0000u), oo[2 * q + 1]);
        }
    }
    __syncthreads();   // fence: all f3 reads done -> sbuf (alias) writes
    #pragma unroll
    for (int q = 0; q < 4; ++q) {
        sbuf[lgrp * 65 + q * 16 + li * 2 + 0] = oo[2 * q + 0];
        sbuf[lgrp * 65 + q * 16 + li * 2 + 1] = oo[2 * q + 1];
    }
    __syncthreads();   // fence: cross-wave sbuf reads below

    const int al = tid & 15, j = tid >> 4;
    const int ga = (row0 >> 3) + al;
    const int ma = ga / 225, aa2 = ga % 225;
    const int hb = j * 8;
    {
        unsigned p0 = pk2(sbuf[al * 65 + hb + 0], sbuf[al * 65 + hb + 1]);
        unsigned p1 = pk2(sbuf[al * 65 + hb + 2], sbuf[al * 65 + hb + 3]);
        unsigned p2 = pk2(sbuf[al * 65 + hb + 4], sbuf[al * 65 + hb + 5]);
        unsigned p3 = pk2(sbuf[al * 65 + hb + 6], sbuf[al * 65 + hb + 7]);
        uint4 st; st.x = p0; st.y = p1; st.z = p2; st.w = p3;
        // vox[m][aa][h]: 16B-aligned ((ma*225+aa2)*64 + hb is mult of 8 us)
        *(uint4*)(vox + ((size_t)(ma * 225 + aa2) * 64 + hb)) = st;
    }
}

// ---------------------------------------------------------------- conv1 MFMA
// R23: TWO images per block (grid 512) — R22's 1-img split doubled per-CU
// A-load L1 traffic (+15 us, kernel is A-load-bound). Anchor-major vox
// staging decode (R21). Barrier every 4 K-steps aligns waves for L1 A-reuse.
__global__ __launch_bounds__(256) void k_conv1m(
    const unsigned short* __restrict__ vox, const unsigned short* __restrict__ w1m,
    const float* __restrict__ b1, unsigned short* __restrict__ out)
{
    const int m0 = blockIdx.x * 2;
    const int tid = threadIdx.x;
    __shared__ unsigned short voxT[2][225 * 66];

    #pragma unroll
    for (int img = 0; img < 2; ++img) {
        const unsigned int* vsrc =
            (const unsigned int*)(vox + (size_t)(m0 + img) * 14400);
        for (int i = tid; i < 7200; i += 256) {
            unsigned v = vsrc[i];
            int a0 = i >> 5;              // 32 dws (64 ch) per anchor
            int c2 = (i & 31) * 2;        // even channel
            *(unsigned*)(&voxT[img][a0 * 66 + c2]) = v;   // 4B-aligned
        }
    }
    __syncthreads();

    const int wv = tid >> 6, lane = tid & 63;
    const int quad = lane >> 4, n = lane & 15;
    const int p = wv * 16 + n;
    const int pe = (p > 62) ? 62 : p;
    const int zo = pe / 9, pr = pe % 9, yo = pr / 3, xo = pr % 3;
    const int basep = zo * 25 + yo * 5 + xo;

    f32x4 acc[2][6];
    #pragma unroll
    for (int g = 0; g < 2; ++g)
        #pragma unroll
        for (int t = 0; t < 6; ++t) acc[g][t] = (f32x4){0.f, 0.f, 0.f, 0.f};

    const uint4* Aptr = (const uint4*)w1m;

    auto loadB = [&](int img, int s) -> uint4 {
        int tap = s >> 1;
        int dz = tap / 9, tr = tap % 9, dy = tr / 3, dx = tr % 3;
        int rw = basep + dz * 25 + dy * 5 + dx;
        int bidx = rw * 66 + (s & 1) * 32 + quad * 8;
        const unsigned int* vp = (const unsigned int*)(&voxT[img][0] + bidx);
        uint4 r; r.x = vp[0]; r.y = vp[1]; r.z = vp[2]; r.w = vp[3];
        return r;
    };

    uint4 Acur[6], Anxt[6];
    uint4 Bcur[2], Bnxt[2];
    #pragma unroll
    for (int t = 0; t < 6; ++t) Acur[t] = Aptr[t * 64 + lane];
    Bcur[0] = loadB(0, 0); Bcur[1] = loadB(1, 0);

    for (int s = 0; s < 54; ++s) {
        if ((s & 3) == 0) __syncthreads();   // align waves for L1 A-reuse
        if (s < 53) {
            Bnxt[0] = loadB(0, s + 1);
            Bnxt[1] = loadB(1, s + 1);
            #pragma unroll
            for (int t = 0; t < 6; ++t)
                Anxt[t] = Aptr[((s + 1) * 6 + t) * 64 + lane];
        }
        bf16x8 bf0 = __builtin_bit_cast(bf16x8, Bcur[0]);
        bf16x8 bf1 = __builtin_bit_cast(bf16x8, Bcur[1]);
        #pragma unroll
        for (int t = 0; t < 6; ++t) {
            bf16x8 af = __builtin_bit_cast(bf16x8, Acur[t]);
            acc[0][t] = __builtin_amdgcn_mfma_f32_16x16x32_bf16(af, bf0, acc[0][t], 0, 0, 0);
            acc[1][t] = __builtin_amdgcn_mfma_f32_16x16x32_bf16(af, bf1, acc[1][t], 0, 0, 0);
        }
        #pragma unroll
        for (int t = 0; t < 6; ++t) Acur[t] = Anxt[t];
        Bcur[0] = Bnxt[0]; Bcur[1] = Bnxt[1];
    }

    if (p < 63) {
        #pragma unroll
        for (int g = 0; g < 2; ++g) {
            #pragma unroll
            for (int t = 0; t < 6; ++t) {
                #pragma unroll
                for (int r = 0; r < 4; r += 2) {
                    int o = t * 16 + quad * 4 + r;
                    unsigned pk = pk2(fmaxf(acc[g][t][r] + b1[o], 0.0f),
                                      fmaxf(acc[g][t][r + 1] + b1[o + 1], 0.0f));
                    out[(m0 + g) * (96 * 63) + o * 63 + p]       = (unsigned short)pk;
                    out[(m0 + g) * (96 * 63) + (o + 1) * 63 + p] = (unsigned short)(pk >> 16);
                }
            }
        }
    }
}

// ---------------------------------------------------------------- conv2 + conv3 + xwi
// conv2 MFMA as R10 (2 images/block) with R22's register B-prefetch
// (bit-identical, confirmed ~neutral-positive at R23). conv3 + xwi: R10
// exact summation order; w3t coalesced.
__global__ __launch_bounds__(256) void k_c23(
    const unsigned short* __restrict__ c1, const unsigned short* __restrict__ w2n,
    const float* __restrict__ b2, const float* __restrict__ w3t,
    const float* __restrict__ b3, const float* __restrict__ wi,
    const float* __restrict__ lb, float* __restrict__ xwi)
{
    const int tid = threadIdx.x;
    const int m0 = blockIdx.x * 2;
    __shared__ unsigned short c1T[2 * 63 * C2S];   // 24696 B
    __shared__ float c2l[2][640];                  // 5120 B
    __shared__ float part[2][4][64];               // 2048 B
    __shared__ float vvl[2][64];                   // 512 B

    const unsigned int* csrc = (const unsigned int*)(c1 + (size_t)m0 * 6048);
    for (int i = tid; i < 6048; i += 256) {
        unsigned v = csrc[i];
        int e0 = 2 * i;
        int mi = (i >= 3024);
        int r0 = e0 - mi * 6048, r1 = r0 + 1;
        int o0 = r0 / 63, p0 = r0 - o0 * 63;
        int o1 = r1 / 63, p1 = r1 - o1 * 63;
        c1T[(mi * 63 + p0) * C2S + o0] = (unsigned short)(v & 0xFFFFu);
        c1T[(mi * 63 + p1) * C2S + o1] = (unsigned short)(v >> 16);
    }
    __syncthreads();

    const int wv = tid >> 6, lane = tid & 63;
    const int quad = lane >> 4, ncol = lane & 15;
    const int arow = lane & 15;
    const int mi = (arow < 10) ? arow / 5 : 1;
    const int zo = (arow < 10) ? arow % 5 : 4;

    f32x4 acc[2];
    acc[0] = (f32x4){0.f, 0.f, 0.f, 0.f};
    acc[1] = (f32x4){0.f, 0.f, 0.f, 0.f};
    const uint4* Bptr = (const uint4*)w2n;

    uint4 Bc[2], Bn[2];
    Bc[0] = Bptr[(wv * 2 + 0) * 64 + lane];
    Bc[1] = Bptr[(wv * 2 + 1) * 64 + lane];

    for (int tap = 0; tap < 27; ++tap) {
        const int dz = tap / 9, r9 = tap % 9;
        const int rowb = (mi * 63 + (zo + dz) * 9 + r9) * C2S;
        #pragma unroll
        for (int sub = 0; sub < 3; ++sub) {
            const int s = tap * 3 + sub;
            const unsigned int* ap =
                (const unsigned int*)(c1T + rowb + sub * 32 + quad * 8);
            uint4 au; au.x = ap[0]; au.y = ap[1]; au.z = ap[2]; au.w = ap[3];
            bf16x8 af = __builtin_bit_cast(bf16x8, au);
            if (s < 80) {
                Bn[0] = Bptr[((s + 1) * 8 + wv * 2 + 0) * 64 + lane];
                Bn[1] = Bptr[((s + 1) * 8 + wv * 2 + 1) * 64 + lane];
            }
            #pragma unroll
            for (int nt = 0; nt < 2; ++nt) {
                bf16x8 bf = __builtin_bit_cast(bf16x8, Bc[nt]);
                acc[nt] = __builtin_amdgcn_mfma_f32_16x16x32_bf16(af, bf, acc[nt], 0, 0, 0);
            }
            Bc[0] = Bn[0]; Bc[1] = Bn[1];
        }
    }

    #pragma unroll
    for (int nt = 0; nt < 2; ++nt) {
        const int o = (wv * 2 + nt) * 16 + ncol;
        const float bias = b2[o];
        #pragma unroll
        for (int reg = 0; reg < 4; ++reg) {
            int rr = quad * 4 + reg;
            if (rr < 10)
                c2l[rr / 5][o * 5 + (rr % 5)] = fmaxf(acc[nt][reg] + bias, 0.0f);
        }
    }
    __syncthreads();

    // conv3: R10 order — per image, 4 partials of 160 K each (u=tid&63,
    // kq=tid>>6), sequential fmaf chain, unroll 8.
    {
        const int u = tid & 63, kq = tid >> 6;
        const int k0 = kq * 160;
        #pragma unroll
        for (int mi2 = 0; mi2 < 2; ++mi2) {
            float acc3 = 0.0f;
            #pragma unroll 8
            for (int k = k0; k < k0 + 160; ++k)
                acc3 = fmaf(c2l[mi2][k], w3t[k * 64 + u], acc3);
            part[mi2][kq][u] = acc3;
        }
    }
    __syncthreads();
    if (tid < 128) {
        int mi2 = tid >> 6, u = tid & 63;
        vvl[mi2][u] = b3[u] + ((part[mi2][0][u] + part[mi2][1][u])
                    + (part[mi2][2][u] + part[mi2][3][u]));
    }
    __syncthreads();

    // xwi: R10 order — sequential k 0..63
    #pragma unroll
    for (int mi2 = 0; mi2 < 2; ++mi2) {
        float a2 = lb[tid];
        #pragma unroll
        for (int k = 0; k < 64; ++k)
            a2 = fmaf(vvl[mi2][k], wi[k * 256 + tid], a2);
        xwi[(m0 + mi2) * 256 + tid] = a2;
    }
}

// ---------------------------------------------------------------- LSTM
// R12: software-pipeline the xwi load one step ahead so its global-load
// latency hides under the 64-FMA recurrent dot (values identical).
__global__ __launch_bounds__(256) void k_lstm(
    const float* __restrict__ xwi, const float* __restrict__ whg,
    const float* __restrict__ h0, const float* __restrict__ c0,
    float* __restrict__ avec, float* __restrict__ hn, float* __restrict__ cn)
{
    const int b = blockIdx.x;
    const int j = threadIdx.x;
    __shared__ __align__(16) float hbuf[64];
    __shared__ float gbuf[256];

    float wh[64];
    #pragma unroll
    for (int k = 0; k < 64; ++k) wh[k] = whg[k * 256 + j];

    if (j < 64) hbuf[j] = h0[b * 64 + j];
    float c = (j < 64) ? c0[b * 64 + j] : 0.0f;
    const bool is_tanh_gate = ((j >> 6) == 2);
    __syncthreads();

    const float4* hb4 = (const float4*)hbuf;
    float xt = xwi[(b * 64 + 0) * 256 + j];
    for (int t = 0; t < 64; ++t) {
        float xt_next = (t < 63) ? xwi[(b * 64 + t + 1) * 256 + j] : 0.0f;
        float g = xt;
        float p[4] = {0.f, 0.f, 0.f, 0.f};
        #pragma unroll
        for (int k4 = 0; k4 < 16; ++k4) {
            float4 h4 = hb4[k4];
            int q = k4 & 3;
            p[q] = fmaf(h4.x, wh[4 * k4 + 0], p[q]);
            p[q] = fmaf(h4.y, wh[4 * k4 + 1], p[q]);
            p[q] = fmaf(h4.z, wh[4 * k4 + 2], p[q]);
            p[q] = fmaf(h4.w, wh[4 * k4 + 3], p[q]);
        }
        g += (p[0] + p[1]) + (p[2] + p[3]);
        gbuf[j] = is_tanh_gate ? tanhf(g) : sigm(g);
        __syncthreads();
        if (j < 64) {
            c = gbuf[64 + j] * c + gbuf[j] * gbuf[128 + j];
            float h = gbuf[192 + j] * tanhf(c);
            hbuf[j] = h;
            avec[(b * 64 + t) * 64 + j] = h;
        }
        __syncthreads();
        xt = xt_next;
    }
    if (j < 64) {
        hn[b * 64 + j] = hbuf[j];
        cn[b * 64 + j] = c;
    }
}

// ---------------------------------------------------------------- launch
extern "C" void kernel_launch(void* const* d_in, const int* in_sizes, int n_in,
                              void* d_out, int out_size, void* d_ws, size_t ws_size,
                              hipStream_t stream) {
    const float* x     = (const float*)d_in[0];
    const float* g_loc = (const float*)d_in[1];
    const float* h0    = (const float*)d_in[2];
    const float* c0    = (const float*)d_in[3];
    const float* pn_w1 = (const float*)d_in[4];
    const float* pn_b1 = (const float*)d_in[5];
    const float* pn_w2 = (const float*)d_in[6];
    const float* pn_b2 = (const float*)d_in[7];
    const float* pn_w3 = (const float*)d_in[8];
    const float* pn_b3 = (const float*)d_in[9];
    const float* aw    = (const float*)d_in[10];
    const float* ab    = (const float*)d_in[11];
    const float* vx_w1 = (const float*)d_in[12];
    const float* vx_b1 = (const float*)d_in[13];
    const float* vx_w2 = (const float*)d_in[14];
    const float* vx_b2 = (const float*)d_in[15];
    const float* vx_w3 = (const float*)d_in[16];
    const float* vx_b3 = (const float*)d_in[17];
    const float* lwi   = (const float*)d_in[18];
    const float* lwh   = (const float*)d_in[19];
    const float* lb    = (const float*)d_in[20];

    float* ws  = (float*)d_ws;
    float* voxr = ws;
    float* c1r  = voxr + SZ_VOX;
    float* c2  = c1r + SZ_C1;         // unused (c2 in LDS; layout stability)
    float* vv  = c2 + SZ_C2;          // unused
    float* xwi = vv + SZ_VV;
    float* w1r = xwi + SZ_XWI;
    float* w2r = w1r + SZ_W1T;
    float* w3t = w2r + SZ_W2T;
    float* w2mr = w3t + SZ_W3T;
    unsigned short* voxh = (unsigned short*)voxr;
    unsigned short* c1h  = (unsigned short*)c1r;
    unsigned short* w1m = (unsigned short*)w1r;
    unsigned short* w2n = (unsigned short*)w2r;
    unsigned short* w2m = (unsigned short*)w2mr;
    unsigned short* w3m = (unsigned short*)xwi;  // aliases xwi head; xwi written later
    int*   idxb = (int*)c1r;          // idx lives in the (not-yet-written) c1 region

    float* out   = (float*)d_out;
    float* avec  = out;                   // 65536
    float* attnw = out + 65536;           // 1843200
    float* hn    = out + 65536 + 1843200; // 1024
    float* cn    = hn + 1024;             // 1024

    k_transpose<<<405, 256, 0, stream>>>(vx_w1, vx_w2, vx_w3, pn_w3, pn_w2,
                                         w1m, w2n, w3t, w3m, w2m);
    k_group<<<1024, 256, 0, stream>>>(x, g_loc, idxb);
    k_mlpm<<<14400, 128, 0, stream>>>(x, g_loc, idxb, pn_w1, pn_b1, w2m, pn_b2,
                                      w3m, pn_b3, aw, ab, voxh, attnw);
    k_conv1m<<<512, 256, 0, stream>>>(voxh, w1m, vx_b1, c1h);
    k_c23<<<512, 256, 0, stream>>>(c1h, w2n, vx_b2, w3t, vx_b3, lwi, lb, xwi);
    k_lstm<<<16, 256, 0, stream>>>(xwi, lwh, h0, c0, avec, hn, cn);
}

// Round 14
// 315.708 us; speedup vs baseline: 1.0878x; 1.0064x over previous
//
#include <hip/hip_runtime.h>
#include <cmath>

// Shapes (fixed by the problem)
#define AT 225      // Z*Y*X anchors
#define NP 128      // points per sample
#define MT 1024     // B*T
#define NSEL 8
#define HD 64

// workspace float offsets
#define SZ_VOX  (1024u*64u*225u)     // region sized in floats; holds bf16 vox [m][aa][h] (R21)
#define SZ_C1   (1024u*96u*63u)      // region holds bf16 c1 (idx aliases head before conv1)
#define SZ_C2   (1024u*128u*5u)      // unused (c2 lives in LDS now)
#define SZ_VV   (1024u*64u)
#define SZ_XWI  (1024u*256u)         // (w3m aliases its head before k_c23 runs)
#define SZ_W1T  (64u*27u*96u)        // holds w1m (bf16 A-frags, conv1)
#define SZ_W2T  (96u*27u*128u)       // holds w2n (bf16 B-frags, conv2)
#define SZ_W3T  (640u*64u)           // w3t (coalesced conv3 weights)
#define SZ_W2M  (512u)               // pn layer2 B-frags (128 uint4)

#define C2S 98                       // conv2 LDS row stride (us), 49 dw (odd)

typedef __attribute__((ext_vector_type(8))) short bf16x8;
typedef __attribute__((ext_vector_type(4))) float f32x4;

__device__ __forceinline__ float sigm(float x) { return 1.0f / (1.0f + expf(-x)); }

__device__ __forceinline__ unsigned short f2bf(float f) {
    unsigned u = __float_as_uint(f);
    unsigned r = u + 0x7FFF + ((u >> 16) & 1);   // RNE
    return (unsigned short)(r >> 16);
}

// R15: real packed bf16 convert (single v_cvt_pk_bf16_f32; no builtin exists).
// NOTE (R16): v_fma_mix_f32_bf16 does NOT exist on gfx950. Do not retry.
// NOTE (R18): for GLOBAL memory, coalescing beats instruction count.
// NOTE (R20/R24): k_mlpm LDS granule boundaries are decisive — R24 aliases
// f3 over fbuf (16896 B, 9 blocks/CU) and won 9 us.
// NOTE (R22): k_conv1m is A-load L1-BW bound — keep 2 images/block.
__device__ __forceinline__ unsigned pk2(float a, float b) {
    unsigned r;
    asm("v_cvt_pk_bf16_f32 %0, %1, %2" : "=v"(r) : "v"(a), "v"(b));
    return r;
}

// ---------------------------------------------------------------- transpose
__global__ __launch_bounds__(256) void k_transpose(
    const float* __restrict__ w1, const float* __restrict__ w2,
    const float* __restrict__ w3, const float* __restrict__ pnw3,
    const float* __restrict__ pnw2,
    unsigned short* __restrict__ w1m, unsigned short* __restrict__ w2n,
    float* __restrict__ w3t, unsigned short* __restrict__ w3m,
    unsigned short* __restrict__ w2m)
{
    int idx = blockIdx.x * 256 + threadIdx.x;
    if (idx < 20736) {
        int lane = idx & 63, r = idx >> 6;
        int t = r % 6, s = r / 6;
        int o = t * 16 + (lane & 15);
        int kb = s * 32 + (lane >> 4) * 8;
        unsigned int dw[4];
        #pragma unroll
        for (int jd = 0; jd < 4; ++jd) {
            int k0 = kb + 2 * jd, k1 = k0 + 1;
            dw[jd] = (unsigned)f2bf(w1[o * 1728 + (k0 & 63) * 27 + (k0 >> 6)]) |
                     ((unsigned)f2bf(w1[o * 1728 + (k1 & 63) * 27 + (k1 >> 6)]) << 16);
        }
        uint4 v; v.x = dw[0]; v.y = dw[1]; v.z = dw[2]; v.w = dw[3];
        ((uint4*)w1m)[idx] = v;
    } else if (idx < 62208) {
        int q = idx - 20736;
        int lane = q & 63, r = q >> 6;
        int nt = r & 7, s = r >> 3;
        int o = nt * 16 + (lane & 15);
        int kb = s * 32 + (lane >> 4) * 8;
        unsigned int dw[4];
        #pragma unroll
        for (int jd = 0; jd < 4; ++jd) {
            int k0 = kb + 2 * jd, k1 = k0 + 1;
            dw[jd] = (unsigned)f2bf(w2[o * 2592 + (k0 % 96) * 27 + (k0 / 96)]) |
                     ((unsigned)f2bf(w2[o * 2592 + (k1 % 96) * 27 + (k1 / 96)]) << 16);
        }
        uint4 v; v.x = dw[0]; v.y = dw[1]; v.z = dw[2]; v.w = dw[3];
        ((uint4*)w2n)[q] = v;
    } else if (idx < 103168) {
        int k = idx - 62208;
        int u = k & 63, r = k >> 6;
        w3t[k] = w3[u * 640 + r];
    } else if (idx < 103424) {
        int k = idx - 103168;
        int lane = k & 63, nt = k >> 6;
        int n = nt * 16 + (lane & 15);
        int kb = (lane >> 4) * 8;
        unsigned int dw[4];
        #pragma unroll
        for (int jd = 0; jd < 4; ++jd) {
            int k0 = kb + 2 * jd;
            dw[jd] = (unsigned)f2bf(pnw3[k0 * 64 + n]) |
                     ((unsigned)f2bf(pnw3[(k0 + 1) * 64 + n]) << 16);
        }
        uint4 v; v.x = dw[0]; v.y = dw[1]; v.z = dw[2]; v.w = dw[3];
        ((uint4*)w3m)[k] = v;
    } else if (idx < 103552) {
        int k = idx - 103424;
        int lane = k & 63, nt = k >> 6;          // nt 0..1
        int n = nt * 16 + (lane & 15);
        int kb = (lane >> 4) * 8;
        unsigned int dw[4];
        #pragma unroll
        for (int jd = 0; jd < 4; ++jd) {
            int k0 = kb + 2 * jd, k1 = k0 + 1;
            float a = (k0 < 16) ? pnw2[k0 * 32 + n] : 0.0f;
            float b = (k1 < 16) ? pnw2[k1 * 32 + n] : 0.0f;
            dw[jd] = (unsigned)f2bf(a) | ((unsigned)f2bf(b) << 16);
        }
        uint4 v; v.x = dw[0]; v.y = dw[1]; v.z = dw[2]; v.w = dw[3];
        ((uint4*)w2m)[k] = v;
    }
}

// ---------------------------------------------------------------- grouping
// R25: grid 1024 -> 2048; block = m*2 + half, each block covers anchor
// range [half*128, half*128+128) (4 ca-iterations). Per-anchor work is
// independent (selection shuffles stay within 8-lane groups; d[] is
// per-iteration local) -> values unchanged IF the loop-body codegen is
// stable. Body is BYTE-IDENTICAL to R10; only the loop header and block
// index mapping changed. HARD GATE: absmax must stay 0.001953125; any
// change -> revert k_group wholesale next round.
__global__ __launch_bounds__(256) void k_group(
    const float* __restrict__ x, const float* __restrict__ g_loc,
    int* __restrict__ idxbuf)
{
    const int m = blockIdx.x >> 1;
    const int half = blockIdx.x & 1;
    const int tid = threadIdx.x;
    __shared__ float pts[3][NP];

    for (int idx = tid; idx < NP * 5; idx += 256) {
        int n = idx / 5, c = idx % 5;
        if (c < 3) pts[c][n] = x[m * (NP * 5) + idx];
    }
    __syncthreads();

    const float gx = g_loc[m * 2 + 0], gy = g_loc[m * 2 + 1];
    const int grp = tid >> 3, li = tid & 7;

    const int ca0 = half * 128;
    for (int ca = ca0; ca < ca0 + 128; ca += 32) {
        const int a = ca + grp;
        const bool active = (a < AT);
        const int aa = active ? a : (AT - 1);
        const int azi = aa / 25, ar = aa % 25, ayi = ar / 5, axi = ar % 5;
        const float fx = ((float)axi - 2.0f) * 0.2f + gx;
        const float fy = ((float)ayi - 2.0f) * 0.2f + gy;
        const float fz = (float)azi * 0.22f + 0.1f;
        const float sa = fx * fx + fy * fy + fz * fz;

        float d[16];
        #pragma unroll
        for (int r = 0; r < 16; ++r) {
            int n = li * 16 + r;
            float px = pts[0][n], py = pts[1][n], pz = pts[2][n];
            d[r] = sa - 2.0f * (fx * px + fy * py + fz * pz)
                      + (px * px + py * py + pz * pz);
        }
        int nidx = 0;
        for (int j = 0; j < NSEL; ++j) {
            float best = 1e30f; int bidx = 0;
            #pragma unroll
            for (int r = 0; r < 16; ++r) {
                int n = li * 16 + r;
                if (d[r] < best) { best = d[r]; bidx = n; }
            }
            #pragma unroll
            for (int off = 1; off < 8; off <<= 1) {
                float ov = __shfl_xor(best, off);
                int   oi = __shfl_xor(bidx, off);
                if (ov < best || (ov == best && oi < bidx)) { best = ov; bidx = oi; }
            }
            if (li == j) nidx = bidx;
            if ((bidx >> 4) == li) {
                int slot = bidx & 15;
                #pragma unroll
                for (int r = 0; r < 16; ++r)
                    if (r == slot) d[r] = 1e30f;
            }
        }
        if (active) idxbuf[(m * AT + a) * NSEL + li] = nidx;
    }
}

// ---------------------------------------------------------------- MLP (MFMA L2+L3)
// R24-verbatim (below 64 us measured; LDS 16896 B = 9 blocks/CU; f3 aliases
// fbuf with hoisted L3 A-frags + fence; anchor-major vox stores).
__global__ __launch_bounds__(128) void k_mlpm(
    const float* __restrict__ x, const float* __restrict__ g_loc,
    const int* __restrict__ idxbuf,
    const float* __restrict__ w1, const float* __restrict__ b1,
    const unsigned short* __restrict__ w2m, const float* __restrict__ b2,
    const unsigned short* __restrict__ w3m, const float* __restrict__ b3,
    const float* __restrict__ aw, const float* __restrict__ ab,
    unsigned short* __restrict__ vox, float* __restrict__ attn_out)
{
    const int tid = threadIdx.x;
    const int row0 = blockIdx.x * 128;
    const int row = row0 + tid;

    __shared__ __align__(16) char smem[16896];
    unsigned int*   fbuf = (unsigned int*)smem;   // stride 17 dw (f1 then f2)
    unsigned int*   f3w  = (unsigned int*)smem;   // stride 33 dw (aliases fbuf)
    float*          pts  = (float*)smem;          // 1280 f32 (aliases head)
    float*          sbuf = (float*)smem;          // 16x65 f32 (aliases head)

    const int m0 = row0 / 1800;
    const int m1 = (row0 + 127) / 1800;
    #pragma unroll
    for (int i = tid; i < 640; i += 128) {
        pts[i]       = x[m0 * 640 + i];
        pts[640 + i] = x[m1 * 640 + i];
    }
    __syncthreads();

    // ---- phase A: layer 1 per-thread, pack f1 to fbuf (K 16..31 zeroed) ----
    const int m = row / 1800;
    const int rr = row % 1800;
    const int a = rr >> 3;
    const int base = (m == m0) ? 0 : 640;

    const int azi = a / 25, ar = a % 25, ayi = ar / 5, axi = ar % 5;
    const float gx = g_loc[m * 2 + 0], gy = g_loc[m * 2 + 1];
    const float fx = ((float)axi - 2.0f) * 0.2f + gx;
    const float fy = ((float)ayi - 2.0f) * 0.2f + gy;
    const float fz = (float)azi * 0.22f + 0.1f;

    const int nidx = idxbuf[row];
    const float in0 = pts[base + nidx * 5 + 0] - fx;
    const float in1 = pts[base + nidx * 5 + 1] - fy;
    const float in2 = pts[base + nidx * 5 + 2] - fz;
    const float in3 = pts[base + nidx * 5 + 3];
    const float in4 = pts[base + nidx * 5 + 4];

    float f1v[16];
    #pragma unroll
    for (int j = 0; j < 16; ++j) {
        float s = b1[j];
        s += in0 * w1[0 * 16 + j] + in1 * w1[1 * 16 + j] + in2 * w1[2 * 16 + j]
           + in3 * w1[3 * 16 + j] + in4 * w1[4 * 16 + j];
        f1v[j] = fmaxf(s, 0.0f);
    }
    __syncthreads();   // all pts (float) reads complete before fbuf writes (alias)
    #pragma unroll
    for (int kd = 0; kd < 8; ++kd)
        fbuf[tid * 17 + kd] = pk2(f1v[2 * kd], f1v[2 * kd + 1]);
    #pragma unroll
    for (int kd = 8; kd < 16; ++kd)
        fbuf[tid * 17 + kd] = 0u;
    // no barrier: L2 A-frags read only this wave's rows (in-order LDS)

    // ---- phase B: MFMA layers (swapped operands) ----
    const int wv = tid >> 6, lane = tid & 63;
    const int quad = lane >> 4, mcol = lane & 15;

    // layer 2: f2[row][n] for n = nt*16 + quad*4 + reg, row = rowbase + mcol
    bf16x8 w2f[2];
    #pragma unroll
    for (int nt = 0; nt < 2; ++nt) {
        uint4 u = ((const uint4*)w2m)[nt * 64 + lane];
        w2f[nt] = __builtin_bit_cast(bf16x8, u);
    }
    const float4* b24 = (const float4*)b2;
    float4 b2q[2];
    #pragma unroll
    for (int nt = 0; nt < 2; ++nt) b2q[nt] = b24[nt * 4 + quad];

    #pragma unroll
    for (int mt = 0; mt < 4; ++mt) {
        const int rowbase = (wv * 4 + mt) * 16;
        const int abase = (rowbase + mcol) * 17 + quad * 4;
        uint4 au;
        au.x = fbuf[abase + 0]; au.y = fbuf[abase + 1];
        au.z = fbuf[abase + 2]; au.w = fbuf[abase + 3];
        bf16x8 af = __builtin_bit_cast(bf16x8, au);
        #pragma unroll
        for (int nt = 0; nt < 2; ++nt) {
            f32x4 z = (f32x4){0.f, 0.f, 0.f, 0.f};
            f32x4 acc = __builtin_amdgcn_mfma_f32_16x16x32_bf16(w2f[nt], af, z, 0, 0, 0);
            float v0 = fmaxf(acc[0] + b2q[nt].x, 0.0f);
            float v1 = fmaxf(acc[1] + b2q[nt].y, 0.0f);
            float v2 = fmaxf(acc[2] + b2q[nt].z, 0.0f);
            float v3 = fmaxf(acc[3] + b2q[nt].w, 0.0f);
            const int dbase = (rowbase + mcol) * 17 + nt * 8 + quad * 2;
            fbuf[dbase + 0] = pk2(v0, v1);
            fbuf[dbase + 1] = pk2(v2, v3);
        }
    }
    // no barrier: L3 A-frag preload reads only this wave's rows (in-order LDS)

    // layer 3: preload ALL 4 tiles' A-frags, then barrier, then MFMA + f3
    // stores (f3 aliases fbuf; cross-wave overlap fenced by the barrier).
    uint4 aA[4];
    #pragma unroll
    for (int mt = 0; mt < 4; ++mt) {
        const int abase = ((wv * 4 + mt) * 16 + mcol) * 17 + quad * 4;
        aA[mt].x = fbuf[abase + 0]; aA[mt].y = fbuf[abase + 1];
        aA[mt].z = fbuf[abase + 2]; aA[mt].w = fbuf[abase + 3];
    }

    bf16x8 w3f[4];
    #pragma unroll
    for (int nt = 0; nt < 4; ++nt) {
        uint4 u = ((const uint4*)w3m)[nt * 64 + lane];
        w3f[nt] = __builtin_bit_cast(bf16x8, u);
    }
    const float4* b34 = (const float4*)b3;
    float4 b3q[4];
    #pragma unroll
    for (int nt = 0; nt < 4; ++nt) b3q[nt] = b34[nt * 4 + quad];

    __syncthreads();   // fence: all waves' fbuf reads done -> f3 (alias) writes

    #pragma unroll
    for (int mt = 0; mt < 4; ++mt) {
        const int rowbase = (wv * 4 + mt) * 16;
        bf16x8 af = __builtin_bit_cast(bf16x8, aA[mt]);
        #pragma unroll
        for (int nt = 0; nt < 4; ++nt) {
            f32x4 z = (f32x4){0.f, 0.f, 0.f, 0.f};
            f32x4 acc = __builtin_amdgcn_mfma_f32_16x16x32_bf16(w3f[nt], af, z, 0, 0, 0);
            float v0 = fmaxf(acc[0] + b3q[nt].x, 0.0f);
            float v1 = fmaxf(acc[1] + b3q[nt].y, 0.0f);
            float v2 = fmaxf(acc[2] + b3q[nt].z, 0.0f);
            float v3 = fmaxf(acc[3] + b3q[nt].w, 0.0f);
            const int dbase = (rowbase + mcol) * 33 + nt * 8 + quad * 2;
            f3w[dbase + 0] = pk2(v0, v1);
            f3w[dbase + 1] = pk2(v2, v3);
        }
    }
    // no barrier: phase C reads only this wave's rows (in-order LDS)

    // ---- phase C: score, softmax, weighted sum ----
    const unsigned int* f3dw = (const unsigned int*)f3w;    // row stride 33 dw
    float s0 = 0.f, s1 = 0.f;
    #pragma unroll
    for (int kd = 0; kd < 32; ++kd) {
        unsigned dw = f3dw[tid * 33 + kd];
        s0 = fmaf(__uint_as_float(dw << 16), aw[2 * kd], s0);
        s1 = fmaf(__uint_as_float(dw & 0xFFFF0000u), aw[2 * kd + 1], s1);
    }
    float sc = s0 + s1 + ab[0];

    float mx = sc;
    #pragma unroll
    for (int off = 1; off < 8; off <<= 1) mx = fmaxf(mx, __shfl_xor(mx, off));
    float e = expf(sc - mx);
    float den = e;
    #pragma unroll
    for (int off = 1; off < 8; off <<= 1) den += __shfl_xor(den, off);
    const float at = e / den;
    attn_out[row] = at;

    // lane li owns h = q*16 + li*2 + {0,1}  (conflict-free b32 reads)
    const int lgrp = tid >> 3;
    const int li = tid & 7;
    const int wl = tid & 63;
    float oo[8];
    #pragma unroll
    for (int i = 0; i < 8; ++i) oo[i] = 0.0f;
    #pragma unroll
    for (int ns = 0; ns < 8; ++ns) {
        float atn = __shfl(at, (wl >> 3) * 8 + ns);
        const int rbase = (lgrp * 8 + ns) * 33;
        #pragma unroll
        for (int q = 0; q < 4; ++q) {
            unsigned dw = f3dw[rbase + q * 8 + li];
            oo[2 * q + 0] = fmaf(atn, __uint_as_float(dw << 16), oo[2 * q + 0]);
            oo[2 * q + 1] = fmaf(atn, __uint_as_float(dw & 0xFFFF0000u), oo[2 * q + 1]);
        }
    }
    __syncthreads();   // fence: all f3 reads done -> sbuf (alias) writes
    #pragma unroll
    for (int q = 0; q < 4; ++q) {
        sbuf[lgrp * 65 + q * 16 + li * 2 + 0] = oo[2 * q + 0];
        sbuf[lgrp * 65 + q * 16 + li * 2 + 1] = oo[2 * q + 1];
    }
    __syncthreads();   // fence: cross-wave sbuf reads below

    const int al = tid & 15, j = tid >> 4;
    const int ga = (row0 >> 3) + al;
    const int ma = ga / 225, aa2 = ga % 225;
    const int hb = j * 8;
    {
        unsigned p0 = pk2(sbuf[al * 65 + hb + 0], sbuf[al * 65 + hb + 1]);
        unsigned p1 = pk2(sbuf[al * 65 + hb + 2], sbuf[al * 65 + hb + 3]);
        unsigned p2 = pk2(sbuf[al * 65 + hb + 4], sbuf[al * 65 + hb + 5]);
        unsigned p3 = pk2(sbuf[al * 65 + hb + 6], sbuf[al * 65 + hb + 7]);
        uint4 st; st.x = p0; st.y = p1; st.z = p2; st.w = p3;
        // vox[m][aa][h]: 16B-aligned ((ma*225+aa2)*64 + hb is mult of 8 us)
        *(uint4*)(vox + ((size_t)(ma * 225 + aa2) * 64 + hb)) = st;
    }
}

// ---------------------------------------------------------------- conv1 MFMA
// R23: TWO images per block (grid 512) — R22's 1-img split doubled per-CU
// A-load L1 traffic (+15 us, kernel is A-load-bound). Anchor-major vox
// staging decode (R21). Barrier every 4 K-steps aligns waves for L1 A-reuse.
__global__ __launch_bounds__(256) void k_conv1m(
    const unsigned short* __restrict__ vox, const unsigned short* __restrict__ w1m,
    const float* __restrict__ b1, unsigned short* __restrict__ out)
{
    const int m0 = blockIdx.x * 2;
    const int tid = threadIdx.x;
    __shared__ unsigned short voxT[2][225 * 66];

    #pragma unroll
    for (int img = 0; img < 2; ++img) {
        const unsigned int* vsrc =
            (const unsigned int*)(vox + (size_t)(m0 + img) * 14400);
        for (int i = tid; i < 7200; i += 256) {
            unsigned v = vsrc[i];
            int a0 = i >> 5;              // 32 dws (64 ch) per anchor
            int c2 = (i & 31) * 2;        // even channel
            *(unsigned*)(&voxT[img][a0 * 66 + c2]) = v;   // 4B-aligned
        }
    }
    __syncthreads();

    const int wv = tid >> 6, lane = tid & 63;
    const int quad = lane >> 4, n = lane & 15;
    const int p = wv * 16 + n;
    const int pe = (p > 62) ? 62 : p;
    const int zo = pe / 9, pr = pe % 9, yo = pr / 3, xo = pr % 3;
    const int basep = zo * 25 + yo * 5 + xo;

    f32x4 acc[2][6];
    #pragma unroll
    for (int g = 0; g < 2; ++g)
        #pragma unroll
        for (int t = 0; t < 6; ++t) acc[g][t] = (f32x4){0.f, 0.f, 0.f, 0.f};

    const uint4* Aptr = (const uint4*)w1m;

    auto loadB = [&](int img, int s) -> uint4 {
        int tap = s >> 1;
        int dz = tap / 9, tr = tap % 9, dy = tr / 3, dx = tr % 3;
        int rw = basep + dz * 25 + dy * 5 + dx;
        int bidx = rw * 66 + (s & 1) * 32 + quad * 8;
        const unsigned int* vp = (const unsigned int*)(&voxT[img][0] + bidx);
        uint4 r; r.x = vp[0]; r.y = vp[1]; r.z = vp[2]; r.w = vp[3];
        return r;
    };

    uint4 Acur[6], Anxt[6];
    uint4 Bcur[2], Bnxt[2];
    #pragma unroll
    for (int t = 0; t < 6; ++t) Acur[t] = Aptr[t * 64 + lane];
    Bcur[0] = loadB(0, 0); Bcur[1] = loadB(1, 0);

    for (int s = 0; s < 54; ++s) {
        if ((s & 3) == 0) __syncthreads();   // align waves for L1 A-reuse
        if (s < 53) {
            Bnxt[0] = loadB(0, s + 1);
            Bnxt[1] = loadB(1, s + 1);
            #pragma unroll
            for (int t = 0; t < 6; ++t)
                Anxt[t] = Aptr[((s + 1) * 6 + t) * 64 + lane];
        }
        bf16x8 bf0 = __builtin_bit_cast(bf16x8, Bcur[0]);
        bf16x8 bf1 = __builtin_bit_cast(bf16x8, Bcur[1]);
        #pragma unroll
        for (int t = 0; t < 6; ++t) {
            bf16x8 af = __builtin_bit_cast(bf16x8, Acur[t]);
            acc[0][t] = __builtin_amdgcn_mfma_f32_16x16x32_bf16(af, bf0, acc[0][t], 0, 0, 0);
            acc[1][t] = __builtin_amdgcn_mfma_f32_16x16x32_bf16(af, bf1, acc[1][t], 0, 0, 0);
        }
        #pragma unroll
        for (int t = 0; t < 6; ++t) Acur[t] = Anxt[t];
        Bcur[0] = Bnxt[0]; Bcur[1] = Bnxt[1];
    }

    if (p < 63) {
        #pragma unroll
        for (int g = 0; g < 2; ++g) {
            #pragma unroll
            for (int t = 0; t < 6; ++t) {
                #pragma unroll
                for (int r = 0; r < 4; r += 2) {
                    int o = t * 16 + quad * 4 + r;
                    unsigned pk = pk2(fmaxf(acc[g][t][r] + b1[o], 0.0f),
                                      fmaxf(acc[g][t][r + 1] + b1[o + 1], 0.0f));
                    out[(m0 + g) * (96 * 63) + o * 63 + p]       = (unsigned short)pk;
                    out[(m0 + g) * (96 * 63) + (o + 1) * 63 + p] = (unsigned short)(pk >> 16);
                }
            }
        }
    }
}

// ---------------------------------------------------------------- conv2 + conv3 + xwi
// conv2 MFMA as R10 (2 images/block) with R22's register B-prefetch
// (bit-identical, confirmed ~neutral-positive at R23). conv3 + xwi: R10
// exact summation order; w3t coalesced.
__global__ __launch_bounds__(256) void k_c23(
    const unsigned short* __restrict__ c1, const unsigned short* __restrict__ w2n,
    const float* __restrict__ b2, const float* __restrict__ w3t,
    const float* __restrict__ b3, const float* __restrict__ wi,
    const float* __restrict__ lb, float* __restrict__ xwi)
{
    const int tid = threadIdx.x;
    const int m0 = blockIdx.x * 2;
    __shared__ unsigned short c1T[2 * 63 * C2S];   // 24696 B
    __shared__ float c2l[2][640];                  // 5120 B
    __shared__ float part[2][4][64];               // 2048 B
    __shared__ float vvl[2][64];                   // 512 B

    const unsigned int* csrc = (const unsigned int*)(c1 + (size_t)m0 * 6048);
    for (int i = tid; i < 6048; i += 256) {
        unsigned v = csrc[i];
        int e0 = 2 * i;
        int mi = (i >= 3024);
        int r0 = e0 - mi * 6048, r1 = r0 + 1;
        int o0 = r0 / 63, p0 = r0 - o0 * 63;
        int o1 = r1 / 63, p1 = r1 - o1 * 63;
        c1T[(mi * 63 + p0) * C2S + o0] = (unsigned short)(v & 0xFFFFu);
        c1T[(mi * 63 + p1) * C2S + o1] = (unsigned short)(v >> 16);
    }
    __syncthreads();

    const int wv = tid >> 6, lane = tid & 63;
    const int quad = lane >> 4, ncol = lane & 15;
    const int arow = lane & 15;
    const int mi = (arow < 10) ? arow / 5 : 1;
    const int zo = (arow < 10) ? arow % 5 : 4;

    f32x4 acc[2];
    acc[0] = (f32x4){0.f, 0.f, 0.f, 0.f};
    acc[1] = (f32x4){0.f, 0.f, 0.f, 0.f};
    const uint4* Bptr = (const uint4*)w2n;

    uint4 Bc[2], Bn[2];
    Bc[0] = Bptr[(wv * 2 + 0) * 64 + lane];
    Bc[1] = Bptr[(wv * 2 + 1) * 64 + lane];

    for (int tap = 0; tap < 27; ++tap) {
        const int dz = tap / 9, r9 = tap % 9;
        const int rowb = (mi * 63 + (zo + dz) * 9 + r9) * C2S;
        #pragma unroll
        for (int sub = 0; sub < 3; ++sub) {
            const int s = tap * 3 + sub;
            const unsigned int* ap =
                (const unsigned int*)(c1T + rowb + sub * 32 + quad * 8);
            uint4 au; au.x = ap[0]; au.y = ap[1]; au.z = ap[2]; au.w = ap[3];
            bf16x8 af = __builtin_bit_cast(bf16x8, au);
            if (s < 80) {
                Bn[0] = Bptr[((s + 1) * 8 + wv * 2 + 0) * 64 + lane];
                Bn[1] = Bptr[((s + 1) * 8 + wv * 2 + 1) * 64 + lane];
            }
            #pragma unroll
            for (int nt = 0; nt < 2; ++nt) {
                bf16x8 bf = __builtin_bit_cast(bf16x8, Bc[nt]);
                acc[nt] = __builtin_amdgcn_mfma_f32_16x16x32_bf16(af, bf, acc[nt], 0, 0, 0);
            }
            Bc[0] = Bn[0]; Bc[1] = Bn[1];
        }
    }

    #pragma unroll
    for (int nt = 0; nt < 2; ++nt) {
        const int o = (wv * 2 + nt) * 16 + ncol;
        const float bias = b2[o];
        #pragma unroll
        for (int reg = 0; reg < 4; ++reg) {
            int rr = quad * 4 + reg;
            if (rr < 10)
                c2l[rr / 5][o * 5 + (rr % 5)] = fmaxf(acc[nt][reg] + bias, 0.0f);
        }
    }
    __syncthreads();

    // conv3: R10 order — per image, 4 partials of 160 K each (u=tid&63,
    // kq=tid>>6), sequential fmaf chain, unroll 8.
    {
        const int u = tid & 63, kq = tid >> 6;
        const int k0 = kq * 160;
        #pragma unroll
        for (int mi2 = 0; mi2 < 2; ++mi2) {
            float acc3 = 0.0f;
            #pragma unroll 8
            for (int k = k0; k < k0 + 160; ++k)
                acc3 = fmaf(c2l[mi2][k], w3t[k * 64 + u], acc3);
            part[mi2][kq][u] = acc3;
        }
    }
    __syncthreads();
    if (tid < 128) {
        int mi2 = tid >> 6, u = tid & 63;
        vvl[mi2][u] = b3[u] + ((part[mi2][0][u] + part[mi2][1][u])
                    + (part[mi2][2][u] + part[mi2][3][u]));
    }
    __syncthreads();

    // xwi: R10 order — sequential k 0..63
    #pragma unroll
    for (int mi2 = 0; mi2 < 2; ++mi2) {
        float a2 = lb[tid];
        #pragma unroll
        for (int k = 0; k < 64; ++k)
            a2 = fmaf(vvl[mi2][k], wi[k * 256 + tid], a2);
        xwi[(m0 + mi2) * 256 + tid] = a2;
    }
}

// ---------------------------------------------------------------- LSTM
// R12: software-pipeline the xwi load one step ahead so its global-load
// latency hides under the 64-FMA recurrent dot (values identical).
__global__ __launch_bounds__(256) void k_lstm(
    const float* __restrict__ xwi, const float* __restrict__ whg,
    const float* __restrict__ h0, const float* __restrict__ c0,
    float* __restrict__ avec, float* __restrict__ hn, float* __restrict__ cn)
{
    const int b = blockIdx.x;
    const int j = threadIdx.x;
    __shared__ __align__(16) float hbuf[64];
    __shared__ float gbuf[256];

    float wh[64];
    #pragma unroll
    for (int k = 0; k < 64; ++k) wh[k] = whg[k * 256 + j];

    if (j < 64) hbuf[j] = h0[b * 64 + j];
    float c = (j < 64) ? c0[b * 64 + j] : 0.0f;
    const bool is_tanh_gate = ((j >> 6) == 2);
    __syncthreads();

    const float4* hb4 = (const float4*)hbuf;
    float xt = xwi[(b * 64 + 0) * 256 + j];
    for (int t = 0; t < 64; ++t) {
        float xt_next = (t < 63) ? xwi[(b * 64 + t + 1) * 256 + j] : 0.0f;
        float g = xt;
        float p[4] = {0.f, 0.f, 0.f, 0.f};
        #pragma unroll
        for (int k4 = 0; k4 < 16; ++k4) {
            float4 h4 = hb4[k4];
            int q = k4 & 3;
            p[q] = fmaf(h4.x, wh[4 * k4 + 0], p[q]);
            p[q] = fmaf(h4.y, wh[4 * k4 + 1], p[q]);
            p[q] = fmaf(h4.z, wh[4 * k4 + 2], p[q]);
            p[q] = fmaf(h4.w, wh[4 * k4 + 3], p[q]);
        }
        g += (p[0] + p[1]) + (p[2] + p[3]);
        gbuf[j] = is_tanh_gate ? tanhf(g) : sigm(g);
        __syncthreads();
        if (j < 64) {
            c = gbuf[64 + j] * c + gbuf[j] * gbuf[128 + j];
            float h = gbuf[192 + j] * tanhf(c);
            hbuf[j] = h;
            avec[(b * 64 + t) * 64 + j] = h;
        }
        __syncthreads();
        xt = xt_next;
    }
    if (j < 64) {
        hn[b * 64 + j] = hbuf[j];
        cn[b * 64 + j] = c;
    }
}

// ---------------------------------------------------------------- launch
extern "C" void kernel_launch(void* const* d_in, const int* in_sizes, int n_in,
                              void* d_out, int out_size, void* d_ws, size_t ws_size,
                              hipStream_t stream) {
    const float* x     = (const float*)d_in[0];
    const float* g_loc = (const float*)d_in[1];
    const float* h0    = (const float*)d_in[2];
    const float* c0    = (const float*)d_in[3];
    const float* pn_w1 = (const float*)d_in[4];
    const float* pn_b1 = (const float*)d_in[5];
    const float* pn_w2 = (const float*)d_in[6];
    const float* pn_b2 = (const float*)d_in[7];
    const float* pn_w3 = (const float*)d_in[8];
    const float* pn_b3 = (const float*)d_in[9];
    const float* aw    = (const float*)d_in[10];
    const float* ab    = (const float*)d_in[11];
    const float* vx_w1 = (const float*)d_in[12];
    const float* vx_b1 = (const float*)d_in[13];
    const float* vx_w2 = (const float*)d_in[14];
    const float* vx_b2 = (const float*)d_in[15];
    const float* vx_w3 = (const float*)d_in[16];
    const float* vx_b3 = (const float*)d_in[17];
    const float* lwi   = (const float*)d_in[18];
    const float* lwh   = (const float*)d_in[19];
    const float* lb    = (const float*)d_in[20];

    float* ws  = (float*)d_ws;
    float* voxr = ws;
    float* c1r  = voxr + SZ_VOX;
    float* c2  = c1r + SZ_C1;         // unused (c2 in LDS; layout stability)
    float* vv  = c2 + SZ_C2;          // unused
    float* xwi = vv + SZ_VV;
    float* w1r = xwi + SZ_XWI;
    float* w2r = w1r + SZ_W1T;
    float* w3t = w2r + SZ_W2T;
    float* w2mr = w3t + SZ_W3T;
    unsigned short* voxh = (unsigned short*)voxr;
    unsigned short* c1h  = (unsigned short*)c1r;
    unsigned short* w1m = (unsigned short*)w1r;
    unsigned short* w2n = (unsigned short*)w2r;
    unsigned short* w2m = (unsigned short*)w2mr;
    unsigned short* w3m = (unsigned short*)xwi;  // aliases xwi head; xwi written later
    int*   idxb = (int*)c1r;          // idx lives in the (not-yet-written) c1 region

    float* out   = (float*)d_out;
    float* avec  = out;                   // 65536
    float* attnw = out + 65536;           // 1843200
    float* hn    = out + 65536 + 1843200; // 1024
    float* cn    = hn + 1024;             // 1024

    k_transpose<<<405, 256, 0, stream>>>(vx_w1, vx_w2, vx_w3, pn_w3, pn_w2,
                                         w1m, w2n, w3t, w3m, w2m);
    k_group<<<2048, 256, 0, stream>>>(x, g_loc, idxb);
    k_mlpm<<<14400, 128, 0, stream>>>(x, g_loc, idxb, pn_w1, pn_b1, w2m, pn_b2,
                                      w3m, pn_b3, aw, ab, voxh, attnw);
    k_conv1m<<<512, 256, 0, stream>>>(voxh, w1m, vx_b1, c1h);
    k_c23<<<512, 256, 0, stream>>>(c1h, w2n, vx_b2, w3t, vx_b3, lwi, lb, xwi);
    k_lstm<<<16, 256, 0, stream>>>(xwi, lwh, h0, c0, avec, hn, cn);
}